// Round 6
// baseline (312.379 us; speedup 1.0000x reference)
//
#include <hip/hip_runtime.h>
#include <hip/hip_bf16.h>

#define LRELU_ALPHA 0.3f
#define LN_EPS 1e-3f

typedef short bf16x8 __attribute__((ext_vector_type(8)));
typedef float f32x4 __attribute__((ext_vector_type(4)));

static __device__ __forceinline__ unsigned short f2bf(float f) {
    union { float f; unsigned u; } v; v.f = f;
    unsigned r = v.u + 0x7fffu + ((v.u >> 16) & 1u);  // RNE
    return (unsigned short)(r >> 16);
}
static __device__ __forceinline__ float bf2f(unsigned short b) {
    union { unsigned u; float f; } v; v.u = ((unsigned)b) << 16;
    return v.f;
}

// ---------------------------------------------------------------------------
// Elementwise fp32 -> bf16 cast (n multiple of 4)
// ---------------------------------------------------------------------------
__global__ void cast_bf16(const float* __restrict__ X, unsigned short* __restrict__ Y, int n) {
    const int i = (blockIdx.x * 256 + threadIdx.x) * 4;
    if (i < n) {
        const float4 v = *(const float4*)(X + i);
        ushort4 o;
        o.x = f2bf(v.x); o.y = f2bf(v.y); o.z = f2bf(v.z); o.w = f2bf(v.w);
        *(ushort4*)(Y + i) = o;
    }
}

// ---------------------------------------------------------------------------
// W (K x N fp32, row-major) -> WT (N x Kp bf16, row-major), zero-pad k in [K,Kp)
// ---------------------------------------------------------------------------
__global__ void transpose_cast(const float* __restrict__ W, unsigned short* __restrict__ WT,
                               int K, int N, int Kp) {
    __shared__ float tile[32][33];
    const int tx = threadIdx.x, ty = threadIdx.y;
    const int kb = blockIdx.y * 32, nb = blockIdx.x * 32;
#pragma unroll
    for (int i = 0; i < 32; i += 8) {
        const int k = kb + ty + i;
        tile[ty + i][tx] = (k < K) ? W[(size_t)k * N + nb + tx] : 0.f;
    }
    __syncthreads();
#pragma unroll
    for (int i = 0; i < 32; i += 8) {
        const int n = nb + ty + i;
        const int k = kb + tx;
        WT[(size_t)n * Kp + k] = f2bf(tile[tx][ty + i]);
    }
}

// ---------------------------------------------------------------------------
// Weight-combine: wc[f,c] = sum_h wa[f,h]*wb[h,c]  (f<F), and the bias row
// bc[c] = sum_h ba[h]*wb[h,c] + bb[c]. One wave per output row, row F = bias.
// ---------------------------------------------------------------------------
__global__ void wcomb_kernel(const float* __restrict__ wa, const float* __restrict__ ba,
                             const float* __restrict__ wb, const float* __restrict__ bb,
                             float* __restrict__ wc, float* __restrict__ bc, int F, int H) {
    const int w = threadIdx.x >> 6, lane = threadIdx.x & 63;
    const int row = blockIdx.x * 4 + w;
    if (row > F) return;
    const float* src = (row < F) ? (wa + (size_t)row * H) : ba;
    float acc[15] = {};
    for (int h = lane; h < H; h += 64) {
        const float a = src[h];
        const float* wr = wb + h * 15;
#pragma unroll
        for (int c = 0; c < 15; ++c) acc[c] += a * wr[c];
    }
#pragma unroll
    for (int c = 0; c < 15; ++c)
#pragma unroll
        for (int off = 32; off > 0; off >>= 1) acc[c] += __shfl_xor(acc[c], off, 64);
    if (lane < 15) {
        if (row < F) wc[row * 15 + lane] = acc[lane];
        else         bc[lane] = acc[lane] + bb[lane];
    }
}

// ---------------------------------------------------------------------------
// bf16 MFMA GEMM: C[M,N] fp32 = A[M,Kp]bf16 @ (BT[N,Kp]bf16)^T + bias
// Block tile 128x64, BK=32, 256 threads = 4 waves, wave tile 64x32 (4x2 mfma).
// ---------------------------------------------------------------------------
#define LDS_STRIDE 40
__global__ __launch_bounds__(256, 4)
void mfma_gemm(const unsigned short* __restrict__ A, int lda,
               const unsigned short* __restrict__ BT, int ldb,
               const float* __restrict__ bias, float* __restrict__ C,
               int M, int N, int K) {
    __shared__ unsigned short As[128 * LDS_STRIDE];
    __shared__ unsigned short Bs[64 * LDS_STRIDE];
    const int tid = threadIdx.x;
    const int w = tid >> 6, lane = tid & 63;
    const int q = lane >> 4, m16 = lane & 15;
    const int wr = (w >> 1) * 64, wc = (w & 1) * 32;
    const int br = blockIdx.y * 128, bc = blockIdx.x * 64;

    const int sr = (tid * 8) >> 5;   // 0..63
    const int sc = (tid * 8) & 31;   // 0,8,16,24

    f32x4 acc[4][2] = {};

    for (int k0 = 0; k0 < K; k0 += 32) {
        const uint4 va0 = *(const uint4*)(A + (size_t)(br + sr) * lda + k0 + sc);
        const uint4 va1 = *(const uint4*)(A + (size_t)(br + sr + 64) * lda + k0 + sc);
        const uint4 vb0 = *(const uint4*)(BT + (size_t)(bc + sr) * ldb + k0 + sc);
        *(uint4*)(As + sr * LDS_STRIDE + sc) = va0;
        *(uint4*)(As + (sr + 64) * LDS_STRIDE + sc) = va1;
        *(uint4*)(Bs + sr * LDS_STRIDE + sc) = vb0;
        __syncthreads();

        bf16x8 af[4], bfr[2];
#pragma unroll
        for (int i = 0; i < 4; ++i)
            af[i] = *(const bf16x8*)(As + (wr + 16 * i + m16) * LDS_STRIDE + q * 8);
#pragma unroll
        for (int j = 0; j < 2; ++j)
            bfr[j] = *(const bf16x8*)(Bs + (wc + 16 * j + m16) * LDS_STRIDE + q * 8);
#pragma unroll
        for (int i = 0; i < 4; ++i)
#pragma unroll
            for (int j = 0; j < 2; ++j)
                acc[i][j] = __builtin_amdgcn_mfma_f32_16x16x32_bf16(af[i], bfr[j], acc[i][j], 0, 0, 0);
        __syncthreads();
    }

#pragma unroll
    for (int i = 0; i < 4; ++i) {
        const int gr = br + wr + 16 * i + q * 4;
#pragma unroll
        for (int j = 0; j < 2; ++j) {
            const int gc = bc + wc + 16 * j + m16;
            const float b = bias[gc];
#pragma unroll
            for (int r = 0; r < 4; ++r)
                C[(size_t)(gr + r) * N + gc] = acc[i][j][r] + b;
        }
    }
}

// ---------------------------------------------------------------------------
// Skinny GEMM, fp32 A: t[M,15] = A[M,lda(F cols)] @ wc[F,15] + bc. Wave/row.
// ---------------------------------------------------------------------------
__global__ void skinny_f32(const float* __restrict__ A, int lda, int F,
                           const float* __restrict__ wc, const float* __restrict__ bc,
                           float* __restrict__ t) {
    const int w = threadIdx.x >> 6, lane = threadIdx.x & 63;
    const int row = blockIdx.x * 4 + w;
    float acc[15] = {};
    for (int f = lane; f < F; f += 64) {
        const float a = A[(size_t)row * lda + f];
        const float* wr = wc + f * 15;
#pragma unroll
        for (int c = 0; c < 15; ++c) acc[c] += a * wr[c];
    }
#pragma unroll
    for (int c = 0; c < 15; ++c)
#pragma unroll
        for (int off = 32; off > 0; off >>= 1) acc[c] += __shfl_xor(acc[c], off, 64);
    if (lane < 15) t[row * 15 + lane] = acc[lane] + bc[lane];
}

// ---------------------------------------------------------------------------
// Skinny GEMM, bf16 A: t[M,15] = A[M,lda(F cols)]bf16 @ wc[F,15] + bc.
// ---------------------------------------------------------------------------
__global__ void skinny_bf16(const unsigned short* __restrict__ A, int lda, int F,
                            const float* __restrict__ wc, const float* __restrict__ bc,
                            float* __restrict__ t) {
    const int w = threadIdx.x >> 6, lane = threadIdx.x & 63;
    const int row = blockIdx.x * 4 + w;
    float acc[15] = {};
    for (int f = lane; f < F; f += 64) {
        const float a = bf2f(A[(size_t)row * lda + f]);
        const float* wr = wc + f * 15;
#pragma unroll
        for (int c = 0; c < 15; ++c) acc[c] += a * wr[c];
    }
#pragma unroll
    for (int c = 0; c < 15; ++c)
#pragma unroll
        for (int off = 32; off > 0; off >>= 1) acc[c] += __shfl_xor(acc[c], off, 64);
    if (lane < 15) t[row * 15 + lane] = acc[lane] + bc[lane];
}

// ---------------------------------------------------------------------------
// Batch diversity: t (N,15) -> dv_part (DIV_JC, N, 5).
// 4 waves x 2 i-rows in registers (~75 live VGPRs, fits 128 cap at 4 w/EU);
// j staged in 256-row LDS tiles padded to 16 floats (ds_read_b128, <=2-way).
// SROA-safe: private arrays indexed by unroll constants only.
// ---------------------------------------------------------------------------
#define DIV_TI 8
#define DIV_JC 4
__global__ __launch_bounds__(256, 4)
void diversity_kernel(const float* __restrict__ t, float* __restrict__ dv_part, int N) {
    const int tid = threadIdx.x;
    const int lane = tid & 63;
    const int g = tid >> 6;                    // wave id = i-group
    const int i0 = blockIdx.x * DIV_TI + g * 2;
    const int jbeg = blockIdx.y * (N / DIV_JC);
    const int jend = jbeg + N / DIV_JC;

    float ti[2][15];
#pragma unroll
    for (int r = 0; r < 2; ++r)
#pragma unroll
        for (int d = 0; d < 15; ++d)
            ti[r][d] = t[(i0 + r) * 15 + d];

    float acc[2][5] = {};

    __shared__ float tj_s[256 * 16];           // 16 KB, rows padded 15->16
    for (int j0 = jbeg; j0 < jend; j0 += 256) {
        __syncthreads();
#pragma unroll
        for (int it = 0; it < 15; ++it) {
            const int idx = it * 256 + tid;    // coalesced global read
            const int row = idx / 15;
            const int col = idx - row * 15;
            tj_s[row * 16 + col] = t[j0 * 15 + idx];
        }
        __syncthreads();
#pragma unroll
        for (int m = 0; m < 4; ++m) {
            const float* rp = tj_s + (m * 64 + lane) * 16;
            const float4 tA = *(const float4*)(rp + 0);
            const float4 tB = *(const float4*)(rp + 4);
            const float4 tC = *(const float4*)(rp + 8);
            const float4 tD = *(const float4*)(rp + 12);
            float tj[15];
            tj[0] = tA.x;  tj[1] = tA.y;  tj[2] = tA.z;  tj[3] = tA.w;
            tj[4] = tB.x;  tj[5] = tB.y;  tj[6] = tB.z;  tj[7] = tB.w;
            tj[8] = tC.x;  tj[9] = tC.y;  tj[10] = tC.z; tj[11] = tC.w;
            tj[12] = tD.x; tj[13] = tD.y; tj[14] = tD.z;
#pragma unroll
            for (int r = 0; r < 2; ++r) {
#pragma unroll
                for (int k = 0; k < 5; ++k) {
                    const float s = fabsf(ti[r][3 * k]     - tj[3 * k])
                                  + fabsf(ti[r][3 * k + 1] - tj[3 * k + 1])
                                  + fabsf(ti[r][3 * k + 2] - tj[3 * k + 2]);
                    acc[r][k] += __expf(-s);
                }
            }
        }
    }

#pragma unroll
    for (int r = 0; r < 2; ++r)
#pragma unroll
        for (int k = 0; k < 5; ++k)
#pragma unroll
            for (int off = 32; off > 0; off >>= 1)
                acc[r][k] += __shfl_xor(acc[r][k], off, 64);

    if (lane == 0) {
        float* dst = dv_part + (size_t)blockIdx.y * N * 5;
#pragma unroll
        for (int r = 0; r < 2; ++r)
#pragma unroll
            for (int k = 0; k < 5; ++k)
                dst[(i0 + r) * 5 + k] = acc[r][k];
    }
}

// ---------------------------------------------------------------------------
// concat([h, sum(dv_part)]) -> LN(center) -> LeakyReLU -> bf16 out (M x Cp),
// zero-padded cols [C,Cp). (Mid-layer: no fp32 output needed.)
// ---------------------------------------------------------------------------
__global__ void ln_lrelu_mid(const float* __restrict__ h, const float* __restrict__ dv_part,
                             const float* __restrict__ beta,
                             unsigned short* __restrict__ out_bf,
                             int H, int D, int Cp, int M) {
    const int i = blockIdx.x;
    const int tid = threadIdx.x;
    const int C = H + D;
    float v[5];
    float s = 0.f, s2 = 0.f;
#pragma unroll
    for (int r = 0; r < 5; ++r) {
        const int c = tid + r * 256;
        if (c < C) {
            float x;
            if (c < H) {
                x = h[(size_t)i * H + c];
            } else {
                const int k = c - H;
                x = 0.f;
#pragma unroll
                for (int jc = 0; jc < DIV_JC; ++jc)
                    x += dv_part[(size_t)jc * M * D + i * D + k];
            }
            v[r] = x; s += x; s2 += x * x;
        }
    }
    __shared__ float rs[4], rs2[4];
    const int lane = tid & 63, wave = tid >> 6;
#pragma unroll
    for (int off = 32; off > 0; off >>= 1) {
        s += __shfl_down(s, off, 64);
        s2 += __shfl_down(s2, off, 64);
    }
    if (lane == 0) { rs[wave] = s; rs2[wave] = s2; }
    __syncthreads();
    const float S = rs[0] + rs[1] + rs[2] + rs[3];
    const float S2 = rs2[0] + rs2[1] + rs2[2] + rs2[3];
    const float mu = S / (float)C;
    const float var = S2 / (float)C - mu * mu;
    const float rstd = rsqrtf(var + LN_EPS);
#pragma unroll
    for (int r = 0; r < 5; ++r) {
        const int c = tid + r * 256;
        if (c < C) {
            float y = (v[r] - mu) * rstd + beta[c];
            y = (y >= 0.f) ? y : LRELU_ALPHA * y;
            out_bf[(size_t)i * Cp + c] = f2bf(y);
        } else if (c < Cp) {
            out_bf[(size_t)i * Cp + c] = 0;  // zero K-pad for next MFMA GEMM
        }
    }
}

// ---------------------------------------------------------------------------
// Final layer: concat -> LN -> LeakyReLU -> fused head dot: out[i] = y.wf + bf
// ---------------------------------------------------------------------------
__global__ void ln_lrelu_head(const float* __restrict__ h, const float* __restrict__ dv_part,
                              const float* __restrict__ beta, const float* __restrict__ wf,
                              const float* __restrict__ bfp, float* __restrict__ out,
                              int H, int D, int M) {
    const int i = blockIdx.x;
    const int tid = threadIdx.x;
    const int C = H + D;
    float v[5];
    float s = 0.f, s2 = 0.f;
#pragma unroll
    for (int r = 0; r < 5; ++r) {
        const int c = tid + r * 256;
        if (c < C) {
            float x;
            if (c < H) {
                x = h[(size_t)i * H + c];
            } else {
                const int k = c - H;
                x = 0.f;
#pragma unroll
                for (int jc = 0; jc < DIV_JC; ++jc)
                    x += dv_part[(size_t)jc * M * D + i * D + k];
            }
            v[r] = x; s += x; s2 += x * x;
        }
    }
    __shared__ float rs[4], rs2[4], rh[4];
    const int lane = tid & 63, wave = tid >> 6;
#pragma unroll
    for (int off = 32; off > 0; off >>= 1) {
        s += __shfl_down(s, off, 64);
        s2 += __shfl_down(s2, off, 64);
    }
    if (lane == 0) { rs[wave] = s; rs2[wave] = s2; }
    __syncthreads();
    const float S = rs[0] + rs[1] + rs[2] + rs[3];
    const float S2 = rs2[0] + rs2[1] + rs2[2] + rs2[3];
    const float mu = S / (float)C;
    const float var = S2 / (float)C - mu * mu;
    const float rstd = rsqrtf(var + LN_EPS);
    float hsum = 0.f;
#pragma unroll
    for (int r = 0; r < 5; ++r) {
        const int c = tid + r * 256;
        if (c < C) {
            float y = (v[r] - mu) * rstd + beta[c];
            y = (y >= 0.f) ? y : LRELU_ALPHA * y;
            hsum += y * wf[c];
        }
    }
#pragma unroll
    for (int off = 32; off > 0; off >>= 1) hsum += __shfl_down(hsum, off, 64);
    if (lane == 0) rh[wave] = hsum;
    __syncthreads();
    if (tid == 0) out[i] = rh[0] + rh[1] + rh[2] + rh[3] + bfp[0];
}

extern "C" void kernel_launch(void* const* d_in, const int* in_sizes, int n_in,
                              void* d_out, int out_size, void* d_ws, size_t ws_size,
                              hipStream_t stream) {
    const float* x     = (const float*)d_in[0];
    const float* w0a   = (const float*)d_in[1];
    const float* b0a   = (const float*)d_in[2];
    const float* w0b   = (const float*)d_in[3];
    const float* b0b   = (const float*)d_in[4];
    const float* beta0 = (const float*)d_in[5];
    const float* w1a   = (const float*)d_in[6];
    const float* b1a   = (const float*)d_in[7];
    const float* w1b   = (const float*)d_in[8];
    const float* b1b   = (const float*)d_in[9];
    const float* beta1 = (const float*)d_in[10];
    const float* wf    = (const float*)d_in[11];
    const float* bf    = (const float*)d_in[12];
    float* out = (float*)d_out;

    const int M = 4096, NF = 512, HID = 1024, C = 1029, CP = 1056;

    // fp32 workspace
    float* h   = (float*)d_ws;                      // 4096 x 1024
    float* t   = h   + (size_t)M * HID;             // 4096 x 15
    float* dvp = t   + (size_t)M * 15;              // DIV_JC x 4096 x 5
    float* wc0 = dvp + (size_t)DIV_JC * M * 5;      // 512 x 15
    float* bc0 = wc0 + (size_t)NF * 15;             // 16
    float* wc1 = bc0 + 16;                          // 1029 x 15
    float* bc1 = wc1 + (size_t)C * 15;              // 16
    // bf16 workspace
    unsigned short* x_bf  = (unsigned short*)(bc1 + 16);             // 4096 x 512
    unsigned short* hc_bf = x_bf  + (size_t)M * NF;                  // 4096 x 1056
    unsigned short* w0aT  = hc_bf + (size_t)M * CP;                  // 1024 x 512
    unsigned short* w1aT  = w0aT  + (size_t)HID * NF;                // 1024 x 1056

    // one-time prep (graph-replayed every call; weights are static inputs)
    cast_bf16<<<(M * NF) / 1024, 256, 0, stream>>>(x, x_bf, M * NF);
    transpose_cast<<<dim3(HID / 32, NF / 32), dim3(32, 8), 0, stream>>>(w0a, w0aT, NF, HID, NF);
    transpose_cast<<<dim3(HID / 32, CP / 32), dim3(32, 8), 0, stream>>>(w1a, w1aT, C, HID, CP);
    wcomb_kernel<<<(NF + 1 + 3) / 4, 256, 0, stream>>>(w0a, b0a, w0b, b0b, wc0, bc0, NF, HID);
    wcomb_kernel<<<(C + 1 + 3) / 4, 256, 0, stream>>>(w1a, b1a, w1b, b1b, wc1, bc1, C, HID);

    // ---- layer 0 ----
    skinny_f32<<<M / 4, 256, 0, stream>>>(x, NF, NF, wc0, bc0, t);       // t0 = x@wc0+bc0
    diversity_kernel<<<dim3(M / DIV_TI, DIV_JC), 256, 0, stream>>>(t, dvp, M);
    mfma_gemm<<<dim3(HID / 64, M / 128), 256, 0, stream>>>(x_bf, NF, w0aT, NF, b0a, h, M, HID, NF);
    ln_lrelu_mid<<<M, 256, 0, stream>>>(h, dvp, beta0, hc_bf, HID, 5, CP, M);

    // ---- layer 1 ----
    skinny_bf16<<<M / 4, 256, 0, stream>>>(hc_bf, CP, C, wc1, bc1, t);   // t1 = hc@wc1+bc1
    diversity_kernel<<<dim3(M / DIV_TI, DIV_JC), 256, 0, stream>>>(t, dvp, M);
    mfma_gemm<<<dim3(HID / 64, M / 128), 256, 0, stream>>>(hc_bf, CP, w1aT, CP, b1a, h, M, HID, CP);
    ln_lrelu_head<<<M, 256, 0, stream>>>(h, dvp, beta1, wf, bf, out, HID, 5, M);
}

// Round 7
// 256.566 us; speedup vs baseline: 1.2175x; 1.2175x over previous
//
#include <hip/hip_runtime.h>
#include <hip/hip_bf16.h>

#define LRELU_ALPHA 0.3f
#define LN_EPS 1e-3f

typedef short bf16x8 __attribute__((ext_vector_type(8)));
typedef float f32x4 __attribute__((ext_vector_type(4)));

static __device__ __forceinline__ unsigned short f2bf(float f) {
    union { float f; unsigned u; } v; v.f = f;
    unsigned r = v.u + 0x7fffu + ((v.u >> 16) & 1u);  // RNE
    return (unsigned short)(r >> 16);
}
static __device__ __forceinline__ float bf2f(unsigned short b) {
    union { unsigned u; float f; } v; v.u = ((unsigned)b) << 16;
    return v.f;
}

// ---------------------------------------------------------------------------
// Elementwise fp32 -> bf16 cast (n multiple of 4)
// ---------------------------------------------------------------------------
__global__ void cast_bf16(const float* __restrict__ X, unsigned short* __restrict__ Y, int n) {
    const int i = (blockIdx.x * 256 + threadIdx.x) * 4;
    if (i < n) {
        const float4 v = *(const float4*)(X + i);
        ushort4 o;
        o.x = f2bf(v.x); o.y = f2bf(v.y); o.z = f2bf(v.z); o.w = f2bf(v.w);
        *(ushort4*)(Y + i) = o;
    }
}

// ---------------------------------------------------------------------------
// W (K x N fp32, row-major) -> WT (N x Kp bf16, row-major), zero-pad k in [K,Kp)
// ---------------------------------------------------------------------------
__global__ void transpose_cast(const float* __restrict__ W, unsigned short* __restrict__ WT,
                               int K, int N, int Kp) {
    __shared__ float tile[32][33];
    const int tx = threadIdx.x, ty = threadIdx.y;
    const int kb = blockIdx.y * 32, nb = blockIdx.x * 32;
#pragma unroll
    for (int i = 0; i < 32; i += 8) {
        const int k = kb + ty + i;
        tile[ty + i][tx] = (k < K) ? W[(size_t)k * N + nb + tx] : 0.f;
    }
    __syncthreads();
#pragma unroll
    for (int i = 0; i < 32; i += 8) {
        const int n = nb + ty + i;
        const int k = kb + tx;
        WT[(size_t)n * Kp + k] = f2bf(tile[tx][ty + i]);
    }
}

// ---------------------------------------------------------------------------
// Weight-combine: wc[f,c] = sum_h wa[f,h]*wb[h,c]  (f<F), and the bias row
// bc[c] = sum_h ba[h]*wb[h,c] + bb[c]. One wave per output row, row F = bias.
// ---------------------------------------------------------------------------
__global__ void wcomb_kernel(const float* __restrict__ wa, const float* __restrict__ ba,
                             const float* __restrict__ wb, const float* __restrict__ bb,
                             float* __restrict__ wc, float* __restrict__ bc, int F, int H) {
    const int w = threadIdx.x >> 6, lane = threadIdx.x & 63;
    const int row = blockIdx.x * 4 + w;
    if (row > F) return;
    const float* src = (row < F) ? (wa + (size_t)row * H) : ba;
    float acc[15] = {};
    for (int h = lane; h < H; h += 64) {
        const float a = src[h];
        const float* wr = wb + h * 15;
#pragma unroll
        for (int c = 0; c < 15; ++c) acc[c] += a * wr[c];
    }
#pragma unroll
    for (int c = 0; c < 15; ++c)
#pragma unroll
        for (int off = 32; off > 0; off >>= 1) acc[c] += __shfl_xor(acc[c], off, 64);
    if (lane < 15) {
        if (row < F) wc[row * 15 + lane] = acc[lane];
        else         bc[lane] = acc[lane] + bb[lane];
    }
}

// ---------------------------------------------------------------------------
// bf16 MFMA GEMM: C[M,N] fp32 = A[M,Kp]bf16 @ (BT[N,Kp]bf16)^T + bias
// Block tile 128x64, BK=32, 256 threads = 4 waves, wave tile 64x32 (4x2 mfma).
// ---------------------------------------------------------------------------
#define LDS_STRIDE 40
__global__ __launch_bounds__(256, 4)
void mfma_gemm(const unsigned short* __restrict__ A, int lda,
               const unsigned short* __restrict__ BT, int ldb,
               const float* __restrict__ bias, float* __restrict__ C,
               int M, int N, int K) {
    __shared__ unsigned short As[128 * LDS_STRIDE];
    __shared__ unsigned short Bs[64 * LDS_STRIDE];
    const int tid = threadIdx.x;
    const int w = tid >> 6, lane = tid & 63;
    const int q = lane >> 4, m16 = lane & 15;
    const int wr = (w >> 1) * 64, wc = (w & 1) * 32;
    const int br = blockIdx.y * 128, bc = blockIdx.x * 64;

    const int sr = (tid * 8) >> 5;   // 0..63
    const int sc = (tid * 8) & 31;   // 0,8,16,24

    f32x4 acc[4][2] = {};

    for (int k0 = 0; k0 < K; k0 += 32) {
        const uint4 va0 = *(const uint4*)(A + (size_t)(br + sr) * lda + k0 + sc);
        const uint4 va1 = *(const uint4*)(A + (size_t)(br + sr + 64) * lda + k0 + sc);
        const uint4 vb0 = *(const uint4*)(BT + (size_t)(bc + sr) * ldb + k0 + sc);
        *(uint4*)(As + sr * LDS_STRIDE + sc) = va0;
        *(uint4*)(As + (sr + 64) * LDS_STRIDE + sc) = va1;
        *(uint4*)(Bs + sr * LDS_STRIDE + sc) = vb0;
        __syncthreads();

        bf16x8 af[4], bfr[2];
#pragma unroll
        for (int i = 0; i < 4; ++i)
            af[i] = *(const bf16x8*)(As + (wr + 16 * i + m16) * LDS_STRIDE + q * 8);
#pragma unroll
        for (int j = 0; j < 2; ++j)
            bfr[j] = *(const bf16x8*)(Bs + (wc + 16 * j + m16) * LDS_STRIDE + q * 8);
#pragma unroll
        for (int i = 0; i < 4; ++i)
#pragma unroll
            for (int j = 0; j < 2; ++j)
                acc[i][j] = __builtin_amdgcn_mfma_f32_16x16x32_bf16(af[i], bfr[j], acc[i][j], 0, 0, 0);
        __syncthreads();
    }

#pragma unroll
    for (int i = 0; i < 4; ++i) {
        const int gr = br + wr + 16 * i + q * 4;
#pragma unroll
        for (int j = 0; j < 2; ++j) {
            const int gc = bc + wc + 16 * j + m16;
            const float b = bias[gc];
#pragma unroll
            for (int r = 0; r < 4; ++r)
                C[(size_t)(gr + r) * N + gc] = acc[i][j][r] + b;
        }
    }
}

// ---------------------------------------------------------------------------
// Skinny GEMM, fp32 A: t[M,15] = A[M,lda(F cols)] @ wc[F,15] + bc. Wave/row.
// ---------------------------------------------------------------------------
__global__ void skinny_f32(const float* __restrict__ A, int lda, int F,
                           const float* __restrict__ wc, const float* __restrict__ bc,
                           float* __restrict__ t) {
    const int w = threadIdx.x >> 6, lane = threadIdx.x & 63;
    const int row = blockIdx.x * 4 + w;
    float acc[15] = {};
    for (int f = lane; f < F; f += 64) {
        const float a = A[(size_t)row * lda + f];
        const float* wr = wc + f * 15;
#pragma unroll
        for (int c = 0; c < 15; ++c) acc[c] += a * wr[c];
    }
#pragma unroll
    for (int c = 0; c < 15; ++c)
#pragma unroll
        for (int off = 32; off > 0; off >>= 1) acc[c] += __shfl_xor(acc[c], off, 64);
    if (lane < 15) t[row * 15 + lane] = acc[lane] + bc[lane];
}

// ---------------------------------------------------------------------------
// Skinny GEMM, bf16 A: t[M,15] = A[M,lda(F cols)]bf16 @ wc[F,15] + bc.
// ---------------------------------------------------------------------------
__global__ void skinny_bf16(const unsigned short* __restrict__ A, int lda, int F,
                            const float* __restrict__ wc, const float* __restrict__ bc,
                            float* __restrict__ t) {
    const int w = threadIdx.x >> 6, lane = threadIdx.x & 63;
    const int row = blockIdx.x * 4 + w;
    float acc[15] = {};
    for (int f = lane; f < F; f += 64) {
        const float a = bf2f(A[(size_t)row * lda + f]);
        const float* wr = wc + f * 15;
#pragma unroll
        for (int c = 0; c < 15; ++c) acc[c] += a * wr[c];
    }
#pragma unroll
    for (int c = 0; c < 15; ++c)
#pragma unroll
        for (int off = 32; off > 0; off >>= 1) acc[c] += __shfl_xor(acc[c], off, 64);
    if (lane < 15) t[row * 15 + lane] = acc[lane] + bc[lane];
}

// ---------------------------------------------------------------------------
// Batch diversity: t (N,15) -> dv_part (DIV_JC, N, 5).
// 4 waves x 4 i-rows in registers (~100 VGPR, fits 128 cap at 4 w/EU).
// LDS j-tile: FLAT 15-float rows (round-3 scheme, measured 0 bank conflicts:
// staging is a straight coalesced copy; reads are ds_read_b32 at stride 15,
// odd stride -> 2 lanes/bank = free). Round 6's 16-pad + b128 reads put every
// lane's 16B read at bank (lane*16)%32 in {0,16} -> ~16-way conflicts, 2.2e7.
// SROA-safe: private arrays indexed by unroll constants only.
// ---------------------------------------------------------------------------
#define DIV_TI 16
#define DIV_JC 4
__global__ __launch_bounds__(256, 4)
void diversity_kernel(const float* __restrict__ t, float* __restrict__ dv_part, int N) {
    const int tid = threadIdx.x;
    const int lane = tid & 63;
    const int g = tid >> 6;                    // wave id = i-group
    const int i0 = blockIdx.x * DIV_TI + g * 4;
    const int jbeg = blockIdx.y * (N / DIV_JC);
    const int jend = jbeg + N / DIV_JC;

    float ti[4][15];
#pragma unroll
    for (int r = 0; r < 4; ++r)
#pragma unroll
        for (int d = 0; d < 15; ++d)
            ti[r][d] = t[(i0 + r) * 15 + d];

    float acc[4][5] = {};

    __shared__ float tj_s[256 * 15];           // 15 KB, flat (stride 15)
    for (int j0 = jbeg; j0 < jend; j0 += 256) {
        __syncthreads();
#pragma unroll
        for (int it = 0; it < 15; ++it)
            tj_s[it * 256 + tid] = t[j0 * 15 + it * 256 + tid];  // straight copy
        __syncthreads();
#pragma unroll
        for (int m = 0; m < 4; ++m) {
            const float* rp = tj_s + (m * 64 + lane) * 15;
#pragma unroll
            for (int r = 0; r < 4; ++r) {
#pragma unroll
                for (int k = 0; k < 5; ++k) {
                    const float s = fabsf(ti[r][3 * k]     - rp[3 * k])
                                  + fabsf(ti[r][3 * k + 1] - rp[3 * k + 1])
                                  + fabsf(ti[r][3 * k + 2] - rp[3 * k + 2]);
                    acc[r][k] += __expf(-s);
                }
            }
        }
    }

#pragma unroll
    for (int r = 0; r < 4; ++r)
#pragma unroll
        for (int k = 0; k < 5; ++k)
#pragma unroll
            for (int off = 32; off > 0; off >>= 1)
                acc[r][k] += __shfl_xor(acc[r][k], off, 64);

    if (lane == 0) {
        float* dst = dv_part + (size_t)blockIdx.y * N * 5;
#pragma unroll
        for (int r = 0; r < 4; ++r)
#pragma unroll
            for (int k = 0; k < 5; ++k)
                dst[(i0 + r) * 5 + k] = acc[r][k];
    }
}

// ---------------------------------------------------------------------------
// concat([h, sum(dv_part)]) -> LN(center) -> LeakyReLU -> bf16 out (M x Cp),
// zero-padded cols [C,Cp). (Mid-layer: no fp32 output needed.)
// ---------------------------------------------------------------------------
__global__ void ln_lrelu_mid(const float* __restrict__ h, const float* __restrict__ dv_part,
                             const float* __restrict__ beta,
                             unsigned short* __restrict__ out_bf,
                             int H, int D, int Cp, int M) {
    const int i = blockIdx.x;
    const int tid = threadIdx.x;
    const int C = H + D;
    float v[5];
    float s = 0.f, s2 = 0.f;
#pragma unroll
    for (int r = 0; r < 5; ++r) {
        const int c = tid + r * 256;
        if (c < C) {
            float x;
            if (c < H) {
                x = h[(size_t)i * H + c];
            } else {
                const int k = c - H;
                x = 0.f;
#pragma unroll
                for (int jc = 0; jc < DIV_JC; ++jc)
                    x += dv_part[(size_t)jc * M * D + i * D + k];
            }
            v[r] = x; s += x; s2 += x * x;
        }
    }
    __shared__ float rs[4], rs2[4];
    const int lane = tid & 63, wave = tid >> 6;
#pragma unroll
    for (int off = 32; off > 0; off >>= 1) {
        s += __shfl_down(s, off, 64);
        s2 += __shfl_down(s2, off, 64);
    }
    if (lane == 0) { rs[wave] = s; rs2[wave] = s2; }
    __syncthreads();
    const float S = rs[0] + rs[1] + rs[2] + rs[3];
    const float S2 = rs2[0] + rs2[1] + rs2[2] + rs2[3];
    const float mu = S / (float)C;
    const float var = S2 / (float)C - mu * mu;
    const float rstd = rsqrtf(var + LN_EPS);
#pragma unroll
    for (int r = 0; r < 5; ++r) {
        const int c = tid + r * 256;
        if (c < C) {
            float y = (v[r] - mu) * rstd + beta[c];
            y = (y >= 0.f) ? y : LRELU_ALPHA * y;
            out_bf[(size_t)i * Cp + c] = f2bf(y);
        } else if (c < Cp) {
            out_bf[(size_t)i * Cp + c] = 0;  // zero K-pad for next MFMA GEMM
        }
    }
}

// ---------------------------------------------------------------------------
// Final layer: concat -> LN -> LeakyReLU -> fused head dot: out[i] = y.wf + bf
// ---------------------------------------------------------------------------
__global__ void ln_lrelu_head(const float* __restrict__ h, const float* __restrict__ dv_part,
                              const float* __restrict__ beta, const float* __restrict__ wf,
                              const float* __restrict__ bfp, float* __restrict__ out,
                              int H, int D, int M) {
    const int i = blockIdx.x;
    const int tid = threadIdx.x;
    const int C = H + D;
    float v[5];
    float s = 0.f, s2 = 0.f;
#pragma unroll
    for (int r = 0; r < 5; ++r) {
        const int c = tid + r * 256;
        if (c < C) {
            float x;
            if (c < H) {
                x = h[(size_t)i * H + c];
            } else {
                const int k = c - H;
                x = 0.f;
#pragma unroll
                for (int jc = 0; jc < DIV_JC; ++jc)
                    x += dv_part[(size_t)jc * M * D + i * D + k];
            }
            v[r] = x; s += x; s2 += x * x;
        }
    }
    __shared__ float rs[4], rs2[4], rh[4];
    const int lane = tid & 63, wave = tid >> 6;
#pragma unroll
    for (int off = 32; off > 0; off >>= 1) {
        s += __shfl_down(s, off, 64);
        s2 += __shfl_down(s2, off, 64);
    }
    if (lane == 0) { rs[wave] = s; rs2[wave] = s2; }
    __syncthreads();
    const float S = rs[0] + rs[1] + rs[2] + rs[3];
    const float S2 = rs2[0] + rs2[1] + rs2[2] + rs2[3];
    const float mu = S / (float)C;
    const float var = S2 / (float)C - mu * mu;
    const float rstd = rsqrtf(var + LN_EPS);
    float hsum = 0.f;
#pragma unroll
    for (int r = 0; r < 5; ++r) {
        const int c = tid + r * 256;
        if (c < C) {
            float y = (v[r] - mu) * rstd + beta[c];
            y = (y >= 0.f) ? y : LRELU_ALPHA * y;
            hsum += y * wf[c];
        }
    }
#pragma unroll
    for (int off = 32; off > 0; off >>= 1) hsum += __shfl_down(hsum, off, 64);
    if (lane == 0) rh[wave] = hsum;
    __syncthreads();
    if (tid == 0) out[i] = rh[0] + rh[1] + rh[2] + rh[3] + bfp[0];
}

extern "C" void kernel_launch(void* const* d_in, const int* in_sizes, int n_in,
                              void* d_out, int out_size, void* d_ws, size_t ws_size,
                              hipStream_t stream) {
    const float* x     = (const float*)d_in[0];
    const float* w0a   = (const float*)d_in[1];
    const float* b0a   = (const float*)d_in[2];
    const float* w0b   = (const float*)d_in[3];
    const float* b0b   = (const float*)d_in[4];
    const float* beta0 = (const float*)d_in[5];
    const float* w1a   = (const float*)d_in[6];
    const float* b1a   = (const float*)d_in[7];
    const float* w1b   = (const float*)d_in[8];
    const float* b1b   = (const float*)d_in[9];
    const float* beta1 = (const float*)d_in[10];
    const float* wf    = (const float*)d_in[11];
    const float* bf    = (const float*)d_in[12];
    float* out = (float*)d_out;

    const int M = 4096, NF = 512, HID = 1024, C = 1029, CP = 1056;

    // fp32 workspace
    float* h   = (float*)d_ws;                      // 4096 x 1024
    float* t   = h   + (size_t)M * HID;             // 4096 x 15
    float* dvp = t   + (size_t)M * 15;              // DIV_JC x 4096 x 5
    float* wc0 = dvp + (size_t)DIV_JC * M * 5;      // 512 x 15
    float* bc0 = wc0 + (size_t)NF * 15;             // 16
    float* wc1 = bc0 + 16;                          // 1029 x 15
    float* bc1 = wc1 + (size_t)C * 15;              // 16
    // bf16 workspace
    unsigned short* x_bf  = (unsigned short*)(bc1 + 16);             // 4096 x 512
    unsigned short* hc_bf = x_bf  + (size_t)M * NF;                  // 4096 x 1056
    unsigned short* w0aT  = hc_bf + (size_t)M * CP;                  // 1024 x 512
    unsigned short* w1aT  = w0aT  + (size_t)HID * NF;                // 1024 x 1056

    // one-time prep (graph-replayed every call; weights are static inputs)
    cast_bf16<<<(M * NF) / 1024, 256, 0, stream>>>(x, x_bf, M * NF);
    transpose_cast<<<dim3(HID / 32, NF / 32), dim3(32, 8), 0, stream>>>(w0a, w0aT, NF, HID, NF);
    transpose_cast<<<dim3(HID / 32, CP / 32), dim3(32, 8), 0, stream>>>(w1a, w1aT, C, HID, CP);
    wcomb_kernel<<<(NF + 1 + 3) / 4, 256, 0, stream>>>(w0a, b0a, w0b, b0b, wc0, bc0, NF, HID);
    wcomb_kernel<<<(C + 1 + 3) / 4, 256, 0, stream>>>(w1a, b1a, w1b, b1b, wc1, bc1, C, HID);

    // ---- layer 0 ----
    skinny_f32<<<M / 4, 256, 0, stream>>>(x, NF, NF, wc0, bc0, t);       // t0 = x@wc0+bc0
    diversity_kernel<<<dim3(M / DIV_TI, DIV_JC), 256, 0, stream>>>(t, dvp, M);
    mfma_gemm<<<dim3(HID / 64, M / 128), 256, 0, stream>>>(x_bf, NF, w0aT, NF, b0a, h, M, HID, NF);
    ln_lrelu_mid<<<M, 256, 0, stream>>>(h, dvp, beta0, hc_bf, HID, 5, CP, M);

    // ---- layer 1 ----
    skinny_bf16<<<M / 4, 256, 0, stream>>>(hc_bf, CP, C, wc1, bc1, t);   // t1 = hc@wc1+bc1
    diversity_kernel<<<dim3(M / DIV_TI, DIV_JC), 256, 0, stream>>>(t, dvp, M);
    mfma_gemm<<<dim3(HID / 64, M / 128), 256, 0, stream>>>(hc_bf, CP, w1aT, CP, b1a, h, M, HID, CP);
    ln_lrelu_head<<<M, 256, 0, stream>>>(h, dvp, beta1, wf, bf, out, HID, 5, M);
}

// Round 8
// 250.186 us; speedup vs baseline: 1.2486x; 1.0255x over previous
//
#include <hip/hip_runtime.h>
#include <hip/hip_bf16.h>

#define LRELU_ALPHA 0.3f
#define LN_EPS 1e-3f

typedef short bf16x8 __attribute__((ext_vector_type(8)));
typedef float f32x4 __attribute__((ext_vector_type(4)));

static __device__ __forceinline__ unsigned short f2bf(float f) {
    union { float f; unsigned u; } v; v.f = f;
    unsigned r = v.u + 0x7fffu + ((v.u >> 16) & 1u);  // RNE
    return (unsigned short)(r >> 16);
}
static __device__ __forceinline__ float bf2f(unsigned short b) {
    union { unsigned u; float f; } v; v.u = ((unsigned)b) << 16;
    return v.f;
}

// async 16B global -> LDS (DMA, no VGPR round-trip). LDS dest must be
// wave-uniform base + lane*16 (m104/m108) -> UNPADDED LDS tiles only.
#define ASYNC_CP16(gsrc, ldst)                                                  \
    __builtin_amdgcn_global_load_lds(                                           \
        (const __attribute__((address_space(1))) unsigned int*)(gsrc),          \
        (__attribute__((address_space(3))) unsigned int*)(ldst), 16, 0, 0)

// ---------------------------------------------------------------------------
// Elementwise fp32 -> bf16 cast (n multiple of 4)
// ---------------------------------------------------------------------------
__global__ void cast_bf16(const float* __restrict__ X, unsigned short* __restrict__ Y, int n) {
    const int i = (blockIdx.x * 256 + threadIdx.x) * 4;
    if (i < n) {
        const float4 v = *(const float4*)(X + i);
        ushort4 o;
        o.x = f2bf(v.x); o.y = f2bf(v.y); o.z = f2bf(v.z); o.w = f2bf(v.w);
        *(ushort4*)(Y + i) = o;
    }
}

// ---------------------------------------------------------------------------
// W (K x N fp32, row-major) -> WT (N x Kp bf16, row-major), zero-pad k in [K,Kp)
// ---------------------------------------------------------------------------
__global__ void transpose_cast(const float* __restrict__ W, unsigned short* __restrict__ WT,
                               int K, int N, int Kp) {
    __shared__ float tile[32][33];
    const int tx = threadIdx.x, ty = threadIdx.y;
    const int kb = blockIdx.y * 32, nb = blockIdx.x * 32;
#pragma unroll
    for (int i = 0; i < 32; i += 8) {
        const int k = kb + ty + i;
        tile[ty + i][tx] = (k < K) ? W[(size_t)k * N + nb + tx] : 0.f;
    }
    __syncthreads();
#pragma unroll
    for (int i = 0; i < 32; i += 8) {
        const int n = nb + ty + i;
        const int k = kb + tx;
        WT[(size_t)n * Kp + k] = f2bf(tile[tx][ty + i]);
    }
}

// ---------------------------------------------------------------------------
// Weight-combine: wc[f,c] = sum_h wa[f,h]*wb[h,c]  (f<F), and the bias row
// bc[c] = sum_h ba[h]*wb[h,c] + bb[c]. One wave per output row, row F = bias.
// ---------------------------------------------------------------------------
__global__ void wcomb_kernel(const float* __restrict__ wa, const float* __restrict__ ba,
                             const float* __restrict__ wb, const float* __restrict__ bb,
                             float* __restrict__ wc, float* __restrict__ bc, int F, int H) {
    const int w = threadIdx.x >> 6, lane = threadIdx.x & 63;
    const int row = blockIdx.x * 4 + w;
    if (row > F) return;
    const float* src = (row < F) ? (wa + (size_t)row * H) : ba;
    float acc[15] = {};
    for (int h = lane; h < H; h += 64) {
        const float a = src[h];
        const float* wr = wb + h * 15;
#pragma unroll
        for (int c = 0; c < 15; ++c) acc[c] += a * wr[c];
    }
#pragma unroll
    for (int c = 0; c < 15; ++c)
#pragma unroll
        for (int off = 32; off > 0; off >>= 1) acc[c] += __shfl_xor(acc[c], off, 64);
    if (lane < 15) {
        if (row < F) wc[row * 15 + lane] = acc[lane];
        else         bc[lane] = acc[lane] + bb[lane];
    }
}

// ---------------------------------------------------------------------------
// bf16 MFMA GEMM: C[M,N] fp32 = A[M,Kp]bf16 @ (BT[N,Kp]bf16)^T + bias
// Block tile 128x64, BK=32, 256 threads = 4 waves, wave tile 64x32 (4x2 mfma).
// Staging via global_load_lds width=16 (m97 lever): UNPADDED LDS rows (64B)
// so each wave's LDS dests are uniform+lane*16; thread tid covers row tid/4,
// 16B chunk tid%4 -> LDS byte offset tid*16 (contiguous per wave).
// ---------------------------------------------------------------------------
__global__ __launch_bounds__(256, 4)
void mfma_gemm(const unsigned short* __restrict__ A, int lda,
               const unsigned short* __restrict__ BT, int ldb,
               const float* __restrict__ bias, float* __restrict__ C,
               int M, int N, int K) {
    __shared__ unsigned short As[128 * 32];   // 8 KB
    __shared__ unsigned short Bs[64 * 32];    // 4 KB
    const int tid = threadIdx.x;
    const int w = tid >> 6, lane = tid & 63;
    const int q = lane >> 4, m16 = lane & 15;
    const int wr = (w >> 1) * 64, wc = (w & 1) * 32;
    const int br = blockIdx.y * 128, bc = blockIdx.x * 64;

    const int sr = tid >> 2;          // 0..63 (staging row)
    const int sc = (tid & 3) * 8;     // 0,8,16,24 (staging col, elements)

    const unsigned short* gA0 = A + (size_t)(br + sr) * lda + sc;
    const unsigned short* gA1 = A + (size_t)(br + sr + 64) * lda + sc;
    const unsigned short* gB0 = BT + (size_t)(bc + sr) * ldb + sc;
    unsigned short* lA0 = As + tid * 8;            // byte tid*16
    unsigned short* lA1 = As + 64 * 32 + tid * 8;  // second half
    unsigned short* lB0 = Bs + tid * 8;

    f32x4 acc[4][2] = {};

    for (int k0 = 0; k0 < K; k0 += 32) {
        ASYNC_CP16(gA0 + k0, lA0);
        ASYNC_CP16(gA1 + k0, lA1);
        ASYNC_CP16(gB0 + k0, lB0);
        __syncthreads();

        bf16x8 af[4], bfr[2];
#pragma unroll
        for (int i = 0; i < 4; ++i)
            af[i] = *(const bf16x8*)(As + (wr + 16 * i + m16) * 32 + q * 8);
#pragma unroll
        for (int j = 0; j < 2; ++j)
            bfr[j] = *(const bf16x8*)(Bs + (wc + 16 * j + m16) * 32 + q * 8);
#pragma unroll
        for (int i = 0; i < 4; ++i)
#pragma unroll
            for (int j = 0; j < 2; ++j)
                acc[i][j] = __builtin_amdgcn_mfma_f32_16x16x32_bf16(af[i], bfr[j], acc[i][j], 0, 0, 0);
        __syncthreads();
    }

#pragma unroll
    for (int i = 0; i < 4; ++i) {
        const int gr = br + wr + 16 * i + q * 4;
#pragma unroll
        for (int j = 0; j < 2; ++j) {
            const int gc = bc + wc + 16 * j + m16;
            const float b = bias[gc];
#pragma unroll
            for (int r = 0; r < 4; ++r)
                C[(size_t)(gr + r) * N + gc] = acc[i][j][r] + b;
        }
    }
}

// ---------------------------------------------------------------------------
// Skinny GEMM, fp32 A: t[M,15] = A[M,lda(F cols)] @ wc[F,15] + bc. Wave/row.
// ---------------------------------------------------------------------------
__global__ void skinny_f32(const float* __restrict__ A, int lda, int F,
                           const float* __restrict__ wc, const float* __restrict__ bc,
                           float* __restrict__ t) {
    const int w = threadIdx.x >> 6, lane = threadIdx.x & 63;
    const int row = blockIdx.x * 4 + w;
    float acc[15] = {};
    for (int f = lane; f < F; f += 64) {
        const float a = A[(size_t)row * lda + f];
        const float* wr = wc + f * 15;
#pragma unroll
        for (int c = 0; c < 15; ++c) acc[c] += a * wr[c];
    }
#pragma unroll
    for (int c = 0; c < 15; ++c)
#pragma unroll
        for (int off = 32; off > 0; off >>= 1) acc[c] += __shfl_xor(acc[c], off, 64);
    if (lane < 15) t[row * 15 + lane] = acc[lane] + bc[lane];
}

// ---------------------------------------------------------------------------
// Skinny GEMM, bf16 A: t[M,15] = A[M,lda(F cols)]bf16 @ wc[F,15] + bc.
// ---------------------------------------------------------------------------
__global__ void skinny_bf16(const unsigned short* __restrict__ A, int lda, int F,
                            const float* __restrict__ wc, const float* __restrict__ bc,
                            float* __restrict__ t) {
    const int w = threadIdx.x >> 6, lane = threadIdx.x & 63;
    const int row = blockIdx.x * 4 + w;
    float acc[15] = {};
    for (int f = lane; f < F; f += 64) {
        const float a = bf2f(A[(size_t)row * lda + f]);
        const float* wr = wc + f * 15;
#pragma unroll
        for (int c = 0; c < 15; ++c) acc[c] += a * wr[c];
    }
#pragma unroll
    for (int c = 0; c < 15; ++c)
#pragma unroll
        for (int off = 32; off > 0; off >>= 1) acc[c] += __shfl_xor(acc[c], off, 64);
    if (lane < 15) t[row * 15 + lane] = acc[lane] + bc[lane];
}

// ---------------------------------------------------------------------------
// Batch diversity: t (N,15) -> dv_part (DIV_JC, N, 5).
// 4 waves x 4 i-rows in registers. LDS j-tile: FLAT 15-float rows (0 bank
// conflicts: coalesced staging; ds_read_b32 stride 15 = odd = 2-way = free).
// SROA-safe: private arrays indexed by unroll constants only.
// ---------------------------------------------------------------------------
#define DIV_TI 16
#define DIV_JC 4
__global__ __launch_bounds__(256, 4)
void diversity_kernel(const float* __restrict__ t, float* __restrict__ dv_part, int N) {
    const int tid = threadIdx.x;
    const int lane = tid & 63;
    const int g = tid >> 6;                    // wave id = i-group
    const int i0 = blockIdx.x * DIV_TI + g * 4;
    const int jbeg = blockIdx.y * (N / DIV_JC);
    const int jend = jbeg + N / DIV_JC;

    float ti[4][15];
#pragma unroll
    for (int r = 0; r < 4; ++r)
#pragma unroll
        for (int d = 0; d < 15; ++d)
            ti[r][d] = t[(i0 + r) * 15 + d];

    float acc[4][5] = {};

    __shared__ float tj_s[256 * 15];           // 15 KB, flat (stride 15)
    for (int j0 = jbeg; j0 < jend; j0 += 256) {
        __syncthreads();
#pragma unroll
        for (int it = 0; it < 15; ++it)
            tj_s[it * 256 + tid] = t[j0 * 15 + it * 256 + tid];  // straight copy
        __syncthreads();
#pragma unroll
        for (int m = 0; m < 4; ++m) {
            const float* rp = tj_s + (m * 64 + lane) * 15;
#pragma unroll
            for (int r = 0; r < 4; ++r) {
#pragma unroll
                for (int k = 0; k < 5; ++k) {
                    const float s = fabsf(ti[r][3 * k]     - rp[3 * k])
                                  + fabsf(ti[r][3 * k + 1] - rp[3 * k + 1])
                                  + fabsf(ti[r][3 * k + 2] - rp[3 * k + 2]);
                    acc[r][k] += __expf(-s);
                }
            }
        }
    }

#pragma unroll
    for (int r = 0; r < 4; ++r)
#pragma unroll
        for (int k = 0; k < 5; ++k)
#pragma unroll
            for (int off = 32; off > 0; off >>= 1)
                acc[r][k] += __shfl_xor(acc[r][k], off, 64);

    if (lane == 0) {
        float* dst = dv_part + (size_t)blockIdx.y * N * 5;
#pragma unroll
        for (int r = 0; r < 4; ++r)
#pragma unroll
            for (int k = 0; k < 5; ++k)
                dst[(i0 + r) * 5 + k] = acc[r][k];
    }
}

// ---------------------------------------------------------------------------
// concat([h, sum(dv_part)]) -> LN(center) -> LeakyReLU -> bf16 out (M x Cp),
// zero-padded cols [C,Cp). (Mid-layer: no fp32 output needed.)
// ---------------------------------------------------------------------------
__global__ void ln_lrelu_mid(const float* __restrict__ h, const float* __restrict__ dv_part,
                             const float* __restrict__ beta,
                             unsigned short* __restrict__ out_bf,
                             int H, int D, int Cp, int M) {
    const int i = blockIdx.x;
    const int tid = threadIdx.x;
    const int C = H + D;
    float v[5];
    float s = 0.f, s2 = 0.f;
#pragma unroll
    for (int r = 0; r < 5; ++r) {
        const int c = tid + r * 256;
        if (c < C) {
            float x;
            if (c < H) {
                x = h[(size_t)i * H + c];
            } else {
                const int k = c - H;
                x = 0.f;
#pragma unroll
                for (int jc = 0; jc < DIV_JC; ++jc)
                    x += dv_part[(size_t)jc * M * D + i * D + k];
            }
            v[r] = x; s += x; s2 += x * x;
        }
    }
    __shared__ float rs[4], rs2[4];
    const int lane = tid & 63, wave = tid >> 6;
#pragma unroll
    for (int off = 32; off > 0; off >>= 1) {
        s += __shfl_down(s, off, 64);
        s2 += __shfl_down(s2, off, 64);
    }
    if (lane == 0) { rs[wave] = s; rs2[wave] = s2; }
    __syncthreads();
    const float S = rs[0] + rs[1] + rs[2] + rs[3];
    const float S2 = rs2[0] + rs2[1] + rs2[2] + rs2[3];
    const float mu = S / (float)C;
    const float var = S2 / (float)C - mu * mu;
    const float rstd = rsqrtf(var + LN_EPS);
#pragma unroll
    for (int r = 0; r < 5; ++r) {
        const int c = tid + r * 256;
        if (c < C) {
            float y = (v[r] - mu) * rstd + beta[c];
            y = (y >= 0.f) ? y : LRELU_ALPHA * y;
            out_bf[(size_t)i * Cp + c] = f2bf(y);
        } else if (c < Cp) {
            out_bf[(size_t)i * Cp + c] = 0;  // zero K-pad for next MFMA GEMM
        }
    }
}

// ---------------------------------------------------------------------------
// Final layer: concat -> LN -> LeakyReLU -> fused head dot: out[i] = y.wf + bf
// ---------------------------------------------------------------------------
__global__ void ln_lrelu_head(const float* __restrict__ h, const float* __restrict__ dv_part,
                              const float* __restrict__ beta, const float* __restrict__ wf,
                              const float* __restrict__ bfp, float* __restrict__ out,
                              int H, int D, int M) {
    const int i = blockIdx.x;
    const int tid = threadIdx.x;
    const int C = H + D;
    float v[5];
    float s = 0.f, s2 = 0.f;
#pragma unroll
    for (int r = 0; r < 5; ++r) {
        const int c = tid + r * 256;
        if (c < C) {
            float x;
            if (c < H) {
                x = h[(size_t)i * H + c];
            } else {
                const int k = c - H;
                x = 0.f;
#pragma unroll
                for (int jc = 0; jc < DIV_JC; ++jc)
                    x += dv_part[(size_t)jc * M * D + i * D + k];
            }
            v[r] = x; s += x; s2 += x * x;
        }
    }
    __shared__ float rs[4], rs2[4], rh[4];
    const int lane = tid & 63, wave = tid >> 6;
#pragma unroll
    for (int off = 32; off > 0; off >>= 1) {
        s += __shfl_down(s, off, 64);
        s2 += __shfl_down(s2, off, 64);
    }
    if (lane == 0) { rs[wave] = s; rs2[wave] = s2; }
    __syncthreads();
    const float S = rs[0] + rs[1] + rs[2] + rs[3];
    const float S2 = rs2[0] + rs2[1] + rs2[2] + rs2[3];
    const float mu = S / (float)C;
    const float var = S2 / (float)C - mu * mu;
    const float rstd = rsqrtf(var + LN_EPS);
    float hsum = 0.f;
#pragma unroll
    for (int r = 0; r < 5; ++r) {
        const int c = tid + r * 256;
        if (c < C) {
            float y = (v[r] - mu) * rstd + beta[c];
            y = (y >= 0.f) ? y : LRELU_ALPHA * y;
            hsum += y * wf[c];
        }
    }
#pragma unroll
    for (int off = 32; off > 0; off >>= 1) hsum += __shfl_down(hsum, off, 64);
    if (lane == 0) rh[wave] = hsum;
    __syncthreads();
    if (tid == 0) out[i] = rh[0] + rh[1] + rh[2] + rh[3] + bfp[0];
}

extern "C" void kernel_launch(void* const* d_in, const int* in_sizes, int n_in,
                              void* d_out, int out_size, void* d_ws, size_t ws_size,
                              hipStream_t stream) {
    const float* x     = (const float*)d_in[0];
    const float* w0a   = (const float*)d_in[1];
    const float* b0a   = (const float*)d_in[2];
    const float* w0b   = (const float*)d_in[3];
    const float* b0b   = (const float*)d_in[4];
    const float* beta0 = (const float*)d_in[5];
    const float* w1a   = (const float*)d_in[6];
    const float* b1a   = (const float*)d_in[7];
    const float* w1b   = (const float*)d_in[8];
    const float* b1b   = (const float*)d_in[9];
    const float* beta1 = (const float*)d_in[10];
    const float* wf    = (const float*)d_in[11];
    const float* bf    = (const float*)d_in[12];
    float* out = (float*)d_out;

    const int M = 4096, NF = 512, HID = 1024, C = 1029, CP = 1056;

    // fp32 workspace (all regions padded to 16-float multiples so the bf16
    // section below stays 16B-aligned -- global_load_lds needs 16B alignment)
    float* h   = (float*)d_ws;                      // 4096 x 1024
    float* t   = h   + (size_t)M * HID;             // 4096 x 15 (61440)
    float* dvp = t   + (size_t)M * 15;              // DIV_JC x 4096 x 5 (81920)
    float* wc0 = dvp + (size_t)DIV_JC * M * 5;      // 512 x 15 (7680)
    float* bc0 = wc0 + (size_t)NF * 15;             // 16
    float* wc1 = bc0 + 16;                          // 1029 x 15 (15435 -> pad 15440)
    float* bc1 = wc1 + 15440;                       // 16
    // bf16 workspace (16B-aligned from here)
    unsigned short* x_bf  = (unsigned short*)(bc1 + 16);             // 4096 x 512
    unsigned short* hc_bf = x_bf  + (size_t)M * NF;                  // 4096 x 1056
    unsigned short* w0aT  = hc_bf + (size_t)M * CP;                  // 1024 x 512
    unsigned short* w1aT  = w0aT  + (size_t)HID * NF;                // 1024 x 1056

    // one-time prep (graph-replayed every call; weights are static inputs)
    cast_bf16<<<(M * NF) / 1024, 256, 0, stream>>>(x, x_bf, M * NF);
    transpose_cast<<<dim3(HID / 32, NF / 32), dim3(32, 8), 0, stream>>>(w0a, w0aT, NF, HID, NF);
    transpose_cast<<<dim3(HID / 32, CP / 32), dim3(32, 8), 0, stream>>>(w1a, w1aT, C, HID, CP);
    wcomb_kernel<<<(NF + 1 + 3) / 4, 256, 0, stream>>>(w0a, b0a, w0b, b0b, wc0, bc0, NF, HID);
    wcomb_kernel<<<(C + 1 + 3) / 4, 256, 0, stream>>>(w1a, b1a, w1b, b1b, wc1, bc1, C, HID);

    // ---- layer 0 ----
    skinny_f32<<<M / 4, 256, 0, stream>>>(x, NF, NF, wc0, bc0, t);       // t0 = x@wc0+bc0
    diversity_kernel<<<dim3(M / DIV_TI, DIV_JC), 256, 0, stream>>>(t, dvp, M);
    mfma_gemm<<<dim3(HID / 64, M / 128), 256, 0, stream>>>(x_bf, NF, w0aT, NF, b0a, h, M, HID, NF);
    ln_lrelu_mid<<<M, 256, 0, stream>>>(h, dvp, beta0, hc_bf, HID, 5, CP, M);

    // ---- layer 1 ----
    skinny_bf16<<<M / 4, 256, 0, stream>>>(hc_bf, CP, C, wc1, bc1, t);   // t1 = hc@wc1+bc1
    diversity_kernel<<<dim3(M / DIV_TI, DIV_JC), 256, 0, stream>>>(t, dvp, M);
    mfma_gemm<<<dim3(HID / 64, M / 128), 256, 0, stream>>>(hc_bf, CP, w1aT, CP, b1a, h, M, HID, CP);
    ln_lrelu_head<<<M, 256, 0, stream>>>(h, dvp, beta1, wf, bf, out, HID, 5, M);
}

// Round 9
// 248.346 us; speedup vs baseline: 1.2578x; 1.0074x over previous
//
#include <hip/hip_runtime.h>
#include <hip/hip_bf16.h>

#define LRELU_ALPHA 0.3f
#define LN_EPS 1e-3f

typedef short bf16x8 __attribute__((ext_vector_type(8)));
typedef float f32x4 __attribute__((ext_vector_type(4)));

static __device__ __forceinline__ unsigned short f2bf(float f) {
    union { float f; unsigned u; } v; v.f = f;
    unsigned r = v.u + 0x7fffu + ((v.u >> 16) & 1u);  // RNE
    return (unsigned short)(r >> 16);
}

// async 16B global -> LDS (DMA). LDS dest = wave-uniform base + lane*16.
#define ASYNC_CP16(gsrc, ldst)                                                  \
    __builtin_amdgcn_global_load_lds(                                           \
        (const __attribute__((address_space(1))) unsigned int*)(gsrc),          \
        (__attribute__((address_space(3))) unsigned int*)(ldst), 16, 0, 0)

// ---------------------------------------------------------------------------
// Fused prep kernel: block-range sections (all independent).
//  [0,2048)      cast x -> x_bf (4 elems/thread)
//  [2048,2560)   transpose w0a (512x1024) -> bT0 rows 0..1023 (ld 512)
//  [2560,3616)   transpose w1a (1029x1024) -> bT1 rows 0..1023 (ld 1056, k-pad 0)
//  [3616,3745)   wcomb0: wc0 = w0a@w0b -> bT0 rows 1024..1038 (transposed),
//                bias row -> be0[1024..1038]
//  [3745,4003)   wcomb1: wc1 = w1a@w1b -> bT1 rows 1024..1038, be1[1024..1038]
//  [4003,4011)   copy b0a -> be0[0..1023], b1a -> be1[0..1023]
// ---------------------------------------------------------------------------
__global__ void prep_kernel(const float* __restrict__ x,
                            const float* __restrict__ w0a, const float* __restrict__ b0a,
                            const float* __restrict__ w0b, const float* __restrict__ b0b,
                            const float* __restrict__ w1a, const float* __restrict__ b1a,
                            const float* __restrict__ w1b, const float* __restrict__ b1b,
                            unsigned short* __restrict__ x_bf,
                            unsigned short* __restrict__ bT0, unsigned short* __restrict__ bT1,
                            float* __restrict__ be0, float* __restrict__ be1) {
    __shared__ float tile[32][33];
    const int b = blockIdx.x, tid = threadIdx.x;

    if (b < 2048) {                       // ---- cast x ----
        const int i = (b * 256 + tid) * 4;
        const float4 v = *(const float4*)(x + i);
        ushort4 o;
        o.x = f2bf(v.x); o.y = f2bf(v.y); o.z = f2bf(v.z); o.w = f2bf(v.w);
        *(ushort4*)(x_bf + i) = o;
        return;
    }
    if (b < 2560) {                       // ---- transpose w0a -> bT0 ----
        const int b2 = b - 2048;
        const int nb = (b2 & 31) * 32, kb = (b2 >> 5) * 32;
        const int tx = tid & 31, ty = tid >> 5;       // 32 x 8
#pragma unroll
        for (int i = 0; i < 4; ++i)
            tile[ty + i * 8][tx] = w0a[(size_t)(kb + ty + i * 8) * 1024 + nb + tx];
        __syncthreads();
#pragma unroll
        for (int i = 0; i < 4; ++i)
            bT0[(size_t)(nb + ty + i * 8) * 512 + kb + tx] = f2bf(tile[tx][ty + i * 8]);
        return;
    }
    if (b < 3616) {                       // ---- transpose w1a -> bT1 ----
        const int b3 = b - 2560;
        const int nb = (b3 & 31) * 32, kb = (b3 >> 5) * 32;   // kb up to 1055
        const int tx = tid & 31, ty = tid >> 5;
#pragma unroll
        for (int i = 0; i < 4; ++i) {
            const int k = kb + ty + i * 8;
            tile[ty + i * 8][tx] = (k < 1029) ? w1a[(size_t)k * 1024 + nb + tx] : 0.f;
        }
        __syncthreads();
#pragma unroll
        for (int i = 0; i < 4; ++i)
            bT1[(size_t)(nb + ty + i * 8) * 1056 + kb + tx] = f2bf(tile[tx][ty + i * 8]);
        return;
    }
    if (b < 4003) {                       // ---- wcomb 0/1 ----
        const int is1 = (b >= 3745);
        const int b4 = b - (is1 ? 3745 : 3616);
        const int w = tid >> 6, lane = tid & 63;
        const int row = b4 * 4 + w;
        const int F = is1 ? 1029 : 512;
        if (row > F) return;
        const float* wa = is1 ? w1a : w0a;
        const float* ba = is1 ? b1a : b0a;
        const float* wb = is1 ? w1b : w0b;
        const float* bb = is1 ? b1b : b0b;
        const float* src = (row < F) ? (wa + (size_t)row * 1024) : ba;
        float acc[15] = {};
        for (int h = lane; h < 1024; h += 64) {
            const float a = src[h];
            const float* wr = wb + h * 15;
#pragma unroll
            for (int c = 0; c < 15; ++c) acc[c] += a * wr[c];
        }
#pragma unroll
        for (int c = 0; c < 15; ++c)
#pragma unroll
            for (int off = 32; off > 0; off >>= 1) acc[c] += __shfl_xor(acc[c], off, 64);
        if (lane < 15) {
            if (row < F) {
                if (is1) bT1[(size_t)(1024 + lane) * 1056 + row] = f2bf(acc[lane]);
                else     bT0[(size_t)(1024 + lane) * 512  + row] = f2bf(acc[lane]);
            } else {
                if (is1) be1[1024 + lane] = acc[lane] + bb[lane];
                else     be0[1024 + lane] = acc[lane] + bb[lane];
            }
        }
        return;
    }
    {                                     // ---- bias copies ----
        const int b6 = b - 4003;
        if (b6 < 4) be0[b6 * 256 + tid] = b0a[b6 * 256 + tid];
        else        be1[(b6 - 4) * 256 + tid] = b1a[(b6 - 4) * 256 + tid];
    }
}

// ---------------------------------------------------------------------------
// bf16 MFMA GEMM: C[M x 1088] fp32 = A[M,lda]bf16 @ (BT[1088,ldb]bf16)^T + be
// Cols 0..1023 = hidden, 1024..1038 = fused skinny output t, rest junk.
// Block tile 128x64, BK=32, 4 waves, wave tile 64x32 (4x2 mfma).
// Staging via global_load_lds width=16, UNPADDED LDS rows (64B).
// ---------------------------------------------------------------------------
__global__ __launch_bounds__(256, 4)
void mfma_gemm(const unsigned short* __restrict__ A, int lda,
               const unsigned short* __restrict__ BT, int ldb,
               const float* __restrict__ bias, float* __restrict__ C, int ldc,
               int K) {
    __shared__ unsigned short As[128 * 32];   // 8 KB
    __shared__ unsigned short Bs[64 * 32];    // 4 KB
    const int tid = threadIdx.x;
    const int w = tid >> 6, lane = tid & 63;
    const int q = lane >> 4, m16 = lane & 15;
    const int wr = (w >> 1) * 64, wc = (w & 1) * 32;
    const int br = blockIdx.y * 128, bc = blockIdx.x * 64;

    const int sr = tid >> 2;          // staging row 0..63
    const int sc = (tid & 3) * 8;     // staging col (elements)

    const unsigned short* gA0 = A + (size_t)(br + sr) * lda + sc;
    const unsigned short* gA1 = A + (size_t)(br + sr + 64) * lda + sc;
    const unsigned short* gB0 = BT + (size_t)(bc + sr) * ldb + sc;
    unsigned short* lA0 = As + tid * 8;
    unsigned short* lA1 = As + 64 * 32 + tid * 8;
    unsigned short* lB0 = Bs + tid * 8;

    f32x4 acc[4][2] = {};

    for (int k0 = 0; k0 < K; k0 += 32) {
        ASYNC_CP16(gA0 + k0, lA0);
        ASYNC_CP16(gA1 + k0, lA1);
        ASYNC_CP16(gB0 + k0, lB0);
        __syncthreads();

        bf16x8 af[4], bfr[2];
#pragma unroll
        for (int i = 0; i < 4; ++i)
            af[i] = *(const bf16x8*)(As + (wr + 16 * i + m16) * 32 + q * 8);
#pragma unroll
        for (int j = 0; j < 2; ++j)
            bfr[j] = *(const bf16x8*)(Bs + (wc + 16 * j + m16) * 32 + q * 8);
#pragma unroll
        for (int i = 0; i < 4; ++i)
#pragma unroll
            for (int j = 0; j < 2; ++j)
                acc[i][j] = __builtin_amdgcn_mfma_f32_16x16x32_bf16(af[i], bfr[j], acc[i][j], 0, 0, 0);
        __syncthreads();
    }

#pragma unroll
    for (int i = 0; i < 4; ++i) {
        const int gr = br + wr + 16 * i + q * 4;
#pragma unroll
        for (int j = 0; j < 2; ++j) {
            const int gc = bc + wc + 16 * j + m16;
            const float b = bias[gc];
#pragma unroll
            for (int r = 0; r < 4; ++r)
                C[(size_t)(gr + r) * ldc + gc] = acc[i][j][r] + b;
        }
    }
}

// ---------------------------------------------------------------------------
// Batch diversity: t (N rows, 15 cols, row stride ldt) -> dv_part (DIV_JC,N,5)
// 4 waves x 4 i-rows in registers; flat 15-float LDS rows (0 conflicts).
// ---------------------------------------------------------------------------
#define DIV_TI 16
#define DIV_JC 4
__global__ __launch_bounds__(256, 4)
void diversity_kernel(const float* __restrict__ t, int ldt,
                      float* __restrict__ dv_part, int N) {
    const int tid = threadIdx.x;
    const int lane = tid & 63;
    const int g = tid >> 6;
    const int i0 = blockIdx.x * DIV_TI + g * 4;
    const int jbeg = blockIdx.y * (N / DIV_JC);
    const int jend = jbeg + N / DIV_JC;

    float ti[4][15];
#pragma unroll
    for (int r = 0; r < 4; ++r)
#pragma unroll
        for (int d = 0; d < 15; ++d)
            ti[r][d] = t[(size_t)(i0 + r) * ldt + d];

    float acc[4][5] = {};

    __shared__ float tj_s[256 * 15];
    for (int j0 = jbeg; j0 < jend; j0 += 256) {
        __syncthreads();
#pragma unroll
        for (int it = 0; it < 15; ++it) {
            const int idx = it * 256 + tid;
            const int row = idx / 15;
            const int col = idx - row * 15;
            tj_s[idx] = t[(size_t)(j0 + row) * ldt + col];
        }
        __syncthreads();
#pragma unroll
        for (int m = 0; m < 4; ++m) {
            const float* rp = tj_s + (m * 64 + lane) * 15;
#pragma unroll
            for (int r = 0; r < 4; ++r) {
#pragma unroll
                for (int k = 0; k < 5; ++k) {
                    const float s = fabsf(ti[r][3 * k]     - rp[3 * k])
                                  + fabsf(ti[r][3 * k + 1] - rp[3 * k + 1])
                                  + fabsf(ti[r][3 * k + 2] - rp[3 * k + 2]);
                    acc[r][k] += __expf(-s);
                }
            }
        }
    }

#pragma unroll
    for (int r = 0; r < 4; ++r)
#pragma unroll
        for (int k = 0; k < 5; ++k)
#pragma unroll
            for (int off = 32; off > 0; off >>= 1)
                acc[r][k] += __shfl_xor(acc[r][k], off, 64);

    if (lane == 0) {
        float* dst = dv_part + (size_t)blockIdx.y * N * 5;
#pragma unroll
        for (int r = 0; r < 4; ++r)
#pragma unroll
            for (int k = 0; k < 5; ++k)
                dst[(i0 + r) * 5 + k] = acc[r][k];
    }
}

// ---------------------------------------------------------------------------
// concat([h(ldh), sum(dv_part)]) -> LN(center) -> LeakyReLU -> bf16 (M x Cp)
// ---------------------------------------------------------------------------
__global__ void ln_lrelu_mid(const float* __restrict__ h, int ldh,
                             const float* __restrict__ dv_part,
                             const float* __restrict__ beta,
                             unsigned short* __restrict__ out_bf,
                             int H, int D, int Cp, int M) {
    const int i = blockIdx.x;
    const int tid = threadIdx.x;
    const int C = H + D;
    float v[5];
    float s = 0.f, s2 = 0.f;
#pragma unroll
    for (int r = 0; r < 5; ++r) {
        const int c = tid + r * 256;
        if (c < C) {
            float x;
            if (c < H) {
                x = h[(size_t)i * ldh + c];
            } else {
                const int k = c - H;
                x = 0.f;
#pragma unroll
                for (int jc = 0; jc < DIV_JC; ++jc)
                    x += dv_part[(size_t)jc * M * D + i * D + k];
            }
            v[r] = x; s += x; s2 += x * x;
        }
    }
    __shared__ float rs[4], rs2[4];
    const int lane = tid & 63, wave = tid >> 6;
#pragma unroll
    for (int off = 32; off > 0; off >>= 1) {
        s += __shfl_down(s, off, 64);
        s2 += __shfl_down(s2, off, 64);
    }
    if (lane == 0) { rs[wave] = s; rs2[wave] = s2; }
    __syncthreads();
    const float S = rs[0] + rs[1] + rs[2] + rs[3];
    const float S2 = rs2[0] + rs2[1] + rs2[2] + rs2[3];
    const float mu = S / (float)C;
    const float var = S2 / (float)C - mu * mu;
    const float rstd = rsqrtf(var + LN_EPS);
#pragma unroll
    for (int r = 0; r < 5; ++r) {
        const int c = tid + r * 256;
        if (c < C) {
            float y = (v[r] - mu) * rstd + beta[c];
            y = (y >= 0.f) ? y : LRELU_ALPHA * y;
            out_bf[(size_t)i * Cp + c] = f2bf(y);
        } else if (c < Cp) {
            out_bf[(size_t)i * Cp + c] = 0;  // zero K-pad for next MFMA GEMM
        }
    }
}

// ---------------------------------------------------------------------------
// Final: concat -> LN -> LeakyReLU -> fused head dot: out[i] = y.wf + bf
// ---------------------------------------------------------------------------
__global__ void ln_lrelu_head(const float* __restrict__ h, int ldh,
                              const float* __restrict__ dv_part,
                              const float* __restrict__ beta, const float* __restrict__ wf,
                              const float* __restrict__ bfp, float* __restrict__ out,
                              int H, int D, int M) {
    const int i = blockIdx.x;
    const int tid = threadIdx.x;
    const int C = H + D;
    float v[5];
    float s = 0.f, s2 = 0.f;
#pragma unroll
    for (int r = 0; r < 5; ++r) {
        const int c = tid + r * 256;
        if (c < C) {
            float x;
            if (c < H) {
                x = h[(size_t)i * ldh + c];
            } else {
                const int k = c - H;
                x = 0.f;
#pragma unroll
                for (int jc = 0; jc < DIV_JC; ++jc)
                    x += dv_part[(size_t)jc * M * D + i * D + k];
            }
            v[r] = x; s += x; s2 += x * x;
        }
    }
    __shared__ float rs[4], rs2[4], rh[4];
    const int lane = tid & 63, wave = tid >> 6;
#pragma unroll
    for (int off = 32; off > 0; off >>= 1) {
        s += __shfl_down(s, off, 64);
        s2 += __shfl_down(s2, off, 64);
    }
    if (lane == 0) { rs[wave] = s; rs2[wave] = s2; }
    __syncthreads();
    const float S = rs[0] + rs[1] + rs[2] + rs[3];
    const float S2 = rs2[0] + rs2[1] + rs2[2] + rs2[3];
    const float mu = S / (float)C;
    const float var = S2 / (float)C - mu * mu;
    const float rstd = rsqrtf(var + LN_EPS);
    float hsum = 0.f;
#pragma unroll
    for (int r = 0; r < 5; ++r) {
        const int c = tid + r * 256;
        if (c < C) {
            float y = (v[r] - mu) * rstd + beta[c];
            y = (y >= 0.f) ? y : LRELU_ALPHA * y;
            hsum += y * wf[c];
        }
    }
#pragma unroll
    for (int off = 32; off > 0; off >>= 1) hsum += __shfl_down(hsum, off, 64);
    if (lane == 0) rh[wave] = hsum;
    __syncthreads();
    if (tid == 0) out[i] = rh[0] + rh[1] + rh[2] + rh[3] + bfp[0];
}

extern "C" void kernel_launch(void* const* d_in, const int* in_sizes, int n_in,
                              void* d_out, int out_size, void* d_ws, size_t ws_size,
                              hipStream_t stream) {
    const float* x     = (const float*)d_in[0];
    const float* w0a   = (const float*)d_in[1];
    const float* b0a   = (const float*)d_in[2];
    const float* w0b   = (const float*)d_in[3];
    const float* b0b   = (const float*)d_in[4];
    const float* beta0 = (const float*)d_in[5];
    const float* w1a   = (const float*)d_in[6];
    const float* b1a   = (const float*)d_in[7];
    const float* w1b   = (const float*)d_in[8];
    const float* b1b   = (const float*)d_in[9];
    const float* beta1 = (const float*)d_in[10];
    const float* wf    = (const float*)d_in[11];
    const float* bf    = (const float*)d_in[12];
    float* out = (float*)d_out;

    const int M = 4096, NF = 512, HID = 1024, CP = 1056, NE = 1088;

    // fp32 workspace (sizes kept multiple-of-16 floats for 16B alignment)
    float* h   = (float*)d_ws;                      // 4096 x 1088 (GEMM out: h | t | junk)
    float* dvp = h   + (size_t)M * NE;              // DIV_JC x 4096 x 5
    float* be0 = dvp + (size_t)DIV_JC * M * 5;      // 1088 (extended bias 0)
    float* be1 = be0 + NE;                          // 1088
    // bf16 workspace (16B-aligned)
    unsigned short* x_bf = (unsigned short*)(be1 + NE);              // 4096 x 512
    unsigned short* hc_bf = x_bf + (size_t)M * NF;                   // 4096 x 1056
    unsigned short* bT0   = hc_bf + (size_t)M * CP;                  // 1088 x 512
    unsigned short* bT1   = bT0 + (size_t)NE * NF;                   // 1088 x 1056

    // ---- fused prep (cast, transposes, weight-combines, bias-extends) ----
    prep_kernel<<<4011, 256, 0, stream>>>(x, w0a, b0a, w0b, b0b, w1a, b1a, w1b, b1b,
                                          x_bf, bT0, bT1, be0, be1);

    // ---- layer 0: GEMM outputs h (cols 0..1023) AND t (cols 1024..1038) ----
    mfma_gemm<<<dim3(NE / 64, M / 128), 256, 0, stream>>>(x_bf, NF, bT0, NF, be0, h, NE, NF);
    diversity_kernel<<<dim3(M / DIV_TI, DIV_JC), 256, 0, stream>>>(h + HID, NE, dvp, M);
    ln_lrelu_mid<<<M, 256, 0, stream>>>(h, NE, dvp, beta0, hc_bf, HID, 5, CP, M);

    // ---- layer 1 ----
    mfma_gemm<<<dim3(NE / 64, M / 128), 256, 0, stream>>>(hc_bf, CP, bT1, CP, be1, h, NE, CP);
    diversity_kernel<<<dim3(M / DIV_TI, DIV_JC), 256, 0, stream>>>(h + HID, NE, dvp, M);
    ln_lrelu_head<<<M, 256, 0, stream>>>(h, NE, dvp, beta1, wf, bf, out, HID, 5, M);
}

// Round 10
// 233.519 us; speedup vs baseline: 1.3377x; 1.0635x over previous
//
#include <hip/hip_runtime.h>
#include <hip/hip_bf16.h>

#define LRELU_ALPHA 0.3f
#define LN_EPS 1e-3f

typedef short bf16x8 __attribute__((ext_vector_type(8)));
typedef float f32x4 __attribute__((ext_vector_type(4)));

static __device__ __forceinline__ unsigned short f2bf(float f) {
    union { float f; unsigned u; } v; v.f = f;
    unsigned r = v.u + 0x7fffu + ((v.u >> 16) & 1u);  // RNE
    return (unsigned short)(r >> 16);
}

// async 16B global -> LDS (DMA). LDS dest = wave-uniform base + lane*16.
#define ASYNC_CP16(gsrc, ldst)                                                  \
    __builtin_amdgcn_global_load_lds(                                           \
        (const __attribute__((address_space(1))) unsigned int*)(gsrc),          \
        (__attribute__((address_space(3))) unsigned int*)(ldst), 16, 0, 0)

#define NE 1152   // extended N: 1024 hidden + 15 fused-skinny + pad to 128-mult

// ---------------------------------------------------------------------------
// Fused prep kernel: block-range sections (all independent).
//  [0,2048)      cast x -> x_bf
//  [2048,2560)   transpose w0a (512x1024) -> bT0 rows 0..1023 (ld 512)
//  [2560,3616)   transpose w1a (1029x1024) -> bT1 rows 0..1023 (ld 1056, k-pad 0)
//  [3616,3745)   wcomb0 -> bT0 rows 1024..1038 + be0[1024..1038]
//  [3745,4003)   wcomb1 -> bT1 rows 1024..1038 + be1[1024..1038]
//  [4003,4011)   copy b0a -> be0[0..1023], b1a -> be1[0..1023]
//  B rows 1039..1151 / C cols 1039..1151 stay poison: multiplied into C cols
//  that are never read; poison-float bias is finite -> harmless.
// ---------------------------------------------------------------------------
__global__ void prep_kernel(const float* __restrict__ x,
                            const float* __restrict__ w0a, const float* __restrict__ b0a,
                            const float* __restrict__ w0b, const float* __restrict__ b0b,
                            const float* __restrict__ w1a, const float* __restrict__ b1a,
                            const float* __restrict__ w1b, const float* __restrict__ b1b,
                            unsigned short* __restrict__ x_bf,
                            unsigned short* __restrict__ bT0, unsigned short* __restrict__ bT1,
                            float* __restrict__ be0, float* __restrict__ be1) {
    __shared__ float tile[32][33];
    const int b = blockIdx.x, tid = threadIdx.x;

    if (b < 2048) {                       // ---- cast x ----
        const int i = (b * 256 + tid) * 4;
        const float4 v = *(const float4*)(x + i);
        ushort4 o;
        o.x = f2bf(v.x); o.y = f2bf(v.y); o.z = f2bf(v.z); o.w = f2bf(v.w);
        *(ushort4*)(x_bf + i) = o;
        return;
    }
    if (b < 2560) {                       // ---- transpose w0a -> bT0 ----
        const int b2 = b - 2048;
        const int nb = (b2 & 31) * 32, kb = (b2 >> 5) * 32;
        const int tx = tid & 31, ty = tid >> 5;       // 32 x 8
#pragma unroll
        for (int i = 0; i < 4; ++i)
            tile[ty + i * 8][tx] = w0a[(size_t)(kb + ty + i * 8) * 1024 + nb + tx];
        __syncthreads();
#pragma unroll
        for (int i = 0; i < 4; ++i)
            bT0[(size_t)(nb + ty + i * 8) * 512 + kb + tx] = f2bf(tile[tx][ty + i * 8]);
        return;
    }
    if (b < 3616) {                       // ---- transpose w1a -> bT1 ----
        const int b3 = b - 2560;
        const int nb = (b3 & 31) * 32, kb = (b3 >> 5) * 32;   // kb up to 1055
        const int tx = tid & 31, ty = tid >> 5;
#pragma unroll
        for (int i = 0; i < 4; ++i) {
            const int k = kb + ty + i * 8;
            tile[ty + i * 8][tx] = (k < 1029) ? w1a[(size_t)k * 1024 + nb + tx] : 0.f;
        }
        __syncthreads();
#pragma unroll
        for (int i = 0; i < 4; ++i)
            bT1[(size_t)(nb + ty + i * 8) * 1056 + kb + tx] = f2bf(tile[tx][ty + i * 8]);
        return;
    }
    if (b < 4003) {                       // ---- wcomb 0/1 ----
        const int is1 = (b >= 3745);
        const int b4 = b - (is1 ? 3745 : 3616);
        const int w = tid >> 6, lane = tid & 63;
        const int row = b4 * 4 + w;
        const int F = is1 ? 1029 : 512;
        if (row > F) return;
        const float* wa = is1 ? w1a : w0a;
        const float* ba = is1 ? b1a : b0a;
        const float* wb = is1 ? w1b : w0b;
        const float* bb = is1 ? b1b : b0b;
        const float* src = (row < F) ? (wa + (size_t)row * 1024) : ba;
        float acc[15] = {};
        for (int h = lane; h < 1024; h += 64) {
            const float a = src[h];
            const float* wr = wb + h * 15;
#pragma unroll
            for (int c = 0; c < 15; ++c) acc[c] += a * wr[c];
        }
#pragma unroll
        for (int c = 0; c < 15; ++c)
#pragma unroll
            for (int off = 32; off > 0; off >>= 1) acc[c] += __shfl_xor(acc[c], off, 64);
        if (lane < 15) {
            if (row < F) {
                if (is1) bT1[(size_t)(1024 + lane) * 1056 + row] = f2bf(acc[lane]);
                else     bT0[(size_t)(1024 + lane) * 512  + row] = f2bf(acc[lane]);
            } else {
                if (is1) be1[1024 + lane] = acc[lane] + bb[lane];
                else     be0[1024 + lane] = acc[lane] + bb[lane];
            }
        }
        return;
    }
    {                                     // ---- bias copies ----
        const int b6 = b - 4003;
        if (b6 < 4) be0[b6 * 256 + tid] = b0a[b6 * 256 + tid];
        else        be1[(b6 - 4) * 256 + tid] = b1a[(b6 - 4) * 256 + tid];
    }
}

// ---------------------------------------------------------------------------
// bf16 MFMA GEMM: C[M x NE] fp32 = A[M,lda]bf16 @ (BT[NE,ldb]bf16)^T + be
// Block tile 128x128 (m93 ladder step), BK=32, 4 waves, wave tile 64x64
// (4x4 16x16x32 mfma, acc[4][4]). Staging: 4 global_load_lds width=16
// issues/thread; UNPADDED LDS (64B rows) per the DMA lane-contiguity rule.
// ---------------------------------------------------------------------------
__global__ __launch_bounds__(256)
void mfma_gemm(const unsigned short* __restrict__ A, int lda,
               const unsigned short* __restrict__ BT, int ldb,
               const float* __restrict__ bias, float* __restrict__ C, int ldc,
               int K) {
    __shared__ unsigned short As[128 * 32];   // 8 KB
    __shared__ unsigned short Bs[128 * 32];   // 8 KB
    const int tid = threadIdx.x;
    const int w = tid >> 6, lane = tid & 63;
    const int q = lane >> 4, m16 = lane & 15;
    const int wr = (w >> 1) * 64, wc = (w & 1) * 64;
    const int br = blockIdx.y * 128, bc = blockIdx.x * 128;

    const int sr = tid >> 2;          // staging row 0..63
    const int sc = (tid & 3) * 8;     // staging col (elements)

    const unsigned short* gA0 = A + (size_t)(br + sr) * lda + sc;
    const unsigned short* gA1 = A + (size_t)(br + sr + 64) * lda + sc;
    const unsigned short* gB0 = BT + (size_t)(bc + sr) * ldb + sc;
    const unsigned short* gB1 = BT + (size_t)(bc + sr + 64) * ldb + sc;
    unsigned short* lA0 = As + tid * 8;
    unsigned short* lA1 = As + 64 * 32 + tid * 8;
    unsigned short* lB0 = Bs + tid * 8;
    unsigned short* lB1 = Bs + 64 * 32 + tid * 8;

    f32x4 acc[4][4] = {};

    for (int k0 = 0; k0 < K; k0 += 32) {
        ASYNC_CP16(gA0 + k0, lA0);
        ASYNC_CP16(gA1 + k0, lA1);
        ASYNC_CP16(gB0 + k0, lB0);
        ASYNC_CP16(gB1 + k0, lB1);
        __syncthreads();

        bf16x8 af[4], bfr[4];
#pragma unroll
        for (int i = 0; i < 4; ++i)
            af[i] = *(const bf16x8*)(As + (wr + 16 * i + m16) * 32 + q * 8);
#pragma unroll
        for (int j = 0; j < 4; ++j)
            bfr[j] = *(const bf16x8*)(Bs + (wc + 16 * j + m16) * 32 + q * 8);
#pragma unroll
        for (int i = 0; i < 4; ++i)
#pragma unroll
            for (int j = 0; j < 4; ++j)
                acc[i][j] = __builtin_amdgcn_mfma_f32_16x16x32_bf16(af[i], bfr[j], acc[i][j], 0, 0, 0);
        __syncthreads();
    }

#pragma unroll
    for (int i = 0; i < 4; ++i) {
        const int gr = br + wr + 16 * i + q * 4;
#pragma unroll
        for (int j = 0; j < 4; ++j) {
            const int gc = bc + wc + 16 * j + m16;
            const float b = bias[gc];
#pragma unroll
            for (int r = 0; r < 4; ++r)
                C[(size_t)(gr + r) * ldc + gc] = acc[i][j][r] + b;
        }
    }
}

// ---------------------------------------------------------------------------
// Batch diversity: t (N rows, 15 cols, row stride ldt) -> dv_part (DIV_JC,N,5)
// 4 waves x 4 i-rows in registers; flat 15-float LDS rows (0 conflicts).
// __launch_bounds__(256,3): VGPR cap ~170 so the ~110 live regs FIT — the
// (256,4) cap of 128 forced alloc to 64 and spilled ~26 regs/thread to
// scratch (r9 counters: WRITE_SIZE 26.9 MB, VGPR 64). 512/110 -> still 4 w/EU.
// ---------------------------------------------------------------------------
#define DIV_TI 16
#define DIV_JC 4
__global__ __launch_bounds__(256, 3)
void diversity_kernel(const float* __restrict__ t, int ldt,
                      float* __restrict__ dv_part, int N) {
    const int tid = threadIdx.x;
    const int lane = tid & 63;
    const int g = tid >> 6;
    const int i0 = blockIdx.x * DIV_TI + g * 4;
    const int jbeg = blockIdx.y * (N / DIV_JC);
    const int jend = jbeg + N / DIV_JC;

    float ti[4][15];
#pragma unroll
    for (int r = 0; r < 4; ++r)
#pragma unroll
        for (int d = 0; d < 15; ++d)
            ti[r][d] = t[(size_t)(i0 + r) * ldt + d];

    float acc[4][5] = {};

    __shared__ float tj_s[256 * 15];
    for (int j0 = jbeg; j0 < jend; j0 += 256) {
        __syncthreads();
#pragma unroll
        for (int it = 0; it < 15; ++it) {
            const int idx = it * 256 + tid;
            const int row = idx / 15;
            const int col = idx - row * 15;
            tj_s[idx] = t[(size_t)(j0 + row) * ldt + col];
        }
        __syncthreads();
#pragma unroll
        for (int m = 0; m < 4; ++m) {
            const float* rp = tj_s + (m * 64 + lane) * 15;
#pragma unroll
            for (int r = 0; r < 4; ++r) {
#pragma unroll
                for (int k = 0; k < 5; ++k) {
                    const float s = fabsf(ti[r][3 * k]     - rp[3 * k])
                                  + fabsf(ti[r][3 * k + 1] - rp[3 * k + 1])
                                  + fabsf(ti[r][3 * k + 2] - rp[3 * k + 2]);
                    acc[r][k] += __expf(-s);
                }
            }
        }
    }

#pragma unroll
    for (int r = 0; r < 4; ++r)
#pragma unroll
        for (int k = 0; k < 5; ++k)
#pragma unroll
            for (int off = 32; off > 0; off >>= 1)
                acc[r][k] += __shfl_xor(acc[r][k], off, 64);

    if (lane == 0) {
        float* dst = dv_part + (size_t)blockIdx.y * N * 5;
#pragma unroll
        for (int r = 0; r < 4; ++r)
#pragma unroll
            for (int k = 0; k < 5; ++k)
                dst[(i0 + r) * 5 + k] = acc[r][k];
    }
}

// ---------------------------------------------------------------------------
// concat([h(ldh), sum(dv_part)]) -> LN(center) -> LeakyReLU -> bf16 (M x Cp)
// ---------------------------------------------------------------------------
__global__ void ln_lrelu_mid(const float* __restrict__ h, int ldh,
                             const float* __restrict__ dv_part,
                             const float* __restrict__ beta,
                             unsigned short* __restrict__ out_bf,
                             int H, int D, int Cp, int M) {
    const int i = blockIdx.x;
    const int tid = threadIdx.x;
    const int C = H + D;
    float v[5];
    float s = 0.f, s2 = 0.f;
#pragma unroll
    for (int r = 0; r < 5; ++r) {
        const int c = tid + r * 256;
        if (c < C) {
            float x;
            if (c < H) {
                x = h[(size_t)i * ldh + c];
            } else {
                const int k = c - H;
                x = 0.f;
#pragma unroll
                for (int jc = 0; jc < DIV_JC; ++jc)
                    x += dv_part[(size_t)jc * M * D + i * D + k];
            }
            v[r] = x; s += x; s2 += x * x;
        }
    }
    __shared__ float rs[4], rs2[4];
    const int lane = tid & 63, wave = tid >> 6;
#pragma unroll
    for (int off = 32; off > 0; off >>= 1) {
        s += __shfl_down(s, off, 64);
        s2 += __shfl_down(s2, off, 64);
    }
    if (lane == 0) { rs[wave] = s; rs2[wave] = s2; }
    __syncthreads();
    const float S = rs[0] + rs[1] + rs[2] + rs[3];
    const float S2 = rs2[0] + rs2[1] + rs2[2] + rs2[3];
    const float mu = S / (float)C;
    const float var = S2 / (float)C - mu * mu;
    const float rstd = rsqrtf(var + LN_EPS);
#pragma unroll
    for (int r = 0; r < 5; ++r) {
        const int c = tid + r * 256;
        if (c < C) {
            float y = (v[r] - mu) * rstd + beta[c];
            y = (y >= 0.f) ? y : LRELU_ALPHA * y;
            out_bf[(size_t)i * Cp + c] = f2bf(y);
        } else if (c < Cp) {
            out_bf[(size_t)i * Cp + c] = 0;  // zero K-pad for next MFMA GEMM
        }
    }
}

// ---------------------------------------------------------------------------
// Final: concat -> LN -> LeakyReLU -> fused head dot: out[i] = y.wf + bf
// ---------------------------------------------------------------------------
__global__ void ln_lrelu_head(const float* __restrict__ h, int ldh,
                              const float* __restrict__ dv_part,
                              const float* __restrict__ beta, const float* __restrict__ wf,
                              const float* __restrict__ bfp, float* __restrict__ out,
                              int H, int D, int M) {
    const int i = blockIdx.x;
    const int tid = threadIdx.x;
    const int C = H + D;
    float v[5];
    float s = 0.f, s2 = 0.f;
#pragma unroll
    for (int r = 0; r < 5; ++r) {
        const int c = tid + r * 256;
        if (c < C) {
            float x;
            if (c < H) {
                x = h[(size_t)i * ldh + c];
            } else {
                const int k = c - H;
                x = 0.f;
#pragma unroll
                for (int jc = 0; jc < DIV_JC; ++jc)
                    x += dv_part[(size_t)jc * M * D + i * D + k];
            }
            v[r] = x; s += x; s2 += x * x;
        }
    }
    __shared__ float rs[4], rs2[4], rh[4];
    const int lane = tid & 63, wave = tid >> 6;
#pragma unroll
    for (int off = 32; off > 0; off >>= 1) {
        s += __shfl_down(s, off, 64);
        s2 += __shfl_down(s2, off, 64);
    }
    if (lane == 0) { rs[wave] = s; rs2[wave] = s2; }
    __syncthreads();
    const float S = rs[0] + rs[1] + rs[2] + rs[3];
    const float S2 = rs2[0] + rs2[1] + rs2[2] + rs2[3];
    const float mu = S / (float)C;
    const float var = S2 / (float)C - mu * mu;
    const float rstd = rsqrtf(var + LN_EPS);
    float hsum = 0.f;
#pragma unroll
    for (int r = 0; r < 5; ++r) {
        const int c = tid + r * 256;
        if (c < C) {
            float y = (v[r] - mu) * rstd + beta[c];
            y = (y >= 0.f) ? y : LRELU_ALPHA * y;
            hsum += y * wf[c];
        }
    }
#pragma unroll
    for (int off = 32; off > 0; off >>= 1) hsum += __shfl_down(hsum, off, 64);
    if (lane == 0) rh[wave] = hsum;
    __syncthreads();
    if (tid == 0) out[i] = rh[0] + rh[1] + rh[2] + rh[3] + bfp[0];
}

extern "C" void kernel_launch(void* const* d_in, const int* in_sizes, int n_in,
                              void* d_out, int out_size, void* d_ws, size_t ws_size,
                              hipStream_t stream) {
    const float* x     = (const float*)d_in[0];
    const float* w0a   = (const float*)d_in[1];
    const float* b0a   = (const float*)d_in[2];
    const float* w0b   = (const float*)d_in[3];
    const float* b0b   = (const float*)d_in[4];
    const float* beta0 = (const float*)d_in[5];
    const float* w1a   = (const float*)d_in[6];
    const float* b1a   = (const float*)d_in[7];
    const float* w1b   = (const float*)d_in[8];
    const float* b1b   = (const float*)d_in[9];
    const float* beta1 = (const float*)d_in[10];
    const float* wf    = (const float*)d_in[11];
    const float* bf    = (const float*)d_in[12];
    float* out = (float*)d_out;

    const int M = 4096, NF = 512, HID = 1024, CP = 1056;

    // fp32 workspace (all offsets multiple-of-4 floats -> 16B aligned)
    float* h   = (float*)d_ws;                      // 4096 x 1152 (h | t | junk)
    float* dvp = h   + (size_t)M * NE;              // DIV_JC x 4096 x 5
    float* be0 = dvp + (size_t)DIV_JC * M * 5;      // 1152 (extended bias 0)
    float* be1 = be0 + NE;                          // 1152
    // bf16 workspace (16B-aligned)
    unsigned short* x_bf = (unsigned short*)(be1 + NE);              // 4096 x 512
    unsigned short* hc_bf = x_bf + (size_t)M * NF;                   // 4096 x 1056
    unsigned short* bT0   = hc_bf + (size_t)M * CP;                  // 1152 x 512
    unsigned short* bT1   = bT0 + (size_t)NE * NF;                   // 1152 x 1056

    // ---- fused prep (cast, transposes, weight-combines, bias-extends) ----
    prep_kernel<<<4011, 256, 0, stream>>>(x, w0a, b0a, w0b, b0b, w1a, b1a, w1b, b1b,
                                          x_bf, bT0, bT1, be0, be1);

    // ---- layer 0: GEMM outputs h (cols 0..1023) AND t (cols 1024..1038) ----
    mfma_gemm<<<dim3(NE / 128, M / 128), 256, 0, stream>>>(x_bf, NF, bT0, NF, be0, h, NE, NF);
    diversity_kernel<<<dim3(M / DIV_TI, DIV_JC), 256, 0, stream>>>(h + HID, NE, dvp, M);
    ln_lrelu_mid<<<M, 256, 0, stream>>>(h, NE, dvp, beta0, hc_bf, HID, 5, CP, M);

    // ---- layer 1 ----
    mfma_gemm<<<dim3(NE / 128, M / 128), 256, 0, stream>>>(hc_bf, CP, bT1, CP, be1, h, NE, CP);
    diversity_kernel<<<dim3(M / DIV_TI, DIV_JC), 256, 0, stream>>>(h + HID, NE, dvp, M);
    ln_lrelu_head<<<M, 256, 0, stream>>>(h, NE, dvp, beta1, wf, bf, out, HID, 5, M);
}

// Round 11
// 216.036 us; speedup vs baseline: 1.4460x; 1.0809x over previous
//
#include <hip/hip_runtime.h>
#include <hip/hip_bf16.h>

#define LRELU_ALPHA 0.3f
#define LN_EPS 1e-3f

typedef short bf16x8 __attribute__((ext_vector_type(8)));
typedef float f32x4 __attribute__((ext_vector_type(4)));

static __device__ __forceinline__ unsigned short f2bf(float f) {
    union { float f; unsigned u; } v; v.f = f;
    unsigned r = v.u + 0x7fffu + ((v.u >> 16) & 1u);  // RNE
    return (unsigned short)(r >> 16);
}

// async 16B global -> LDS (DMA). LDS dest = wave-uniform base + lane*16.
#define ASYNC_CP16(gsrc, ldst)                                                  \
    __builtin_amdgcn_global_load_lds(                                           \
        (const __attribute__((address_space(1))) unsigned int*)(gsrc),          \
        (__attribute__((address_space(3))) unsigned int*)(ldst), 16, 0, 0)

#define NE 1152   // extended B-rows: 1024 hidden + 15 fused-skinny + pad

// ---------------------------------------------------------------------------
// Fused prep kernel (unchanged from r9/r10): cast x, transpose big weights,
// weight-combine skinny into B rows 1024..1038, extended biases.
// ---------------------------------------------------------------------------
__global__ void prep_kernel(const float* __restrict__ x,
                            const float* __restrict__ w0a, const float* __restrict__ b0a,
                            const float* __restrict__ w0b, const float* __restrict__ b0b,
                            const float* __restrict__ w1a, const float* __restrict__ b1a,
                            const float* __restrict__ w1b, const float* __restrict__ b1b,
                            unsigned short* __restrict__ x_bf,
                            unsigned short* __restrict__ bT0, unsigned short* __restrict__ bT1,
                            float* __restrict__ be0, float* __restrict__ be1) {
    __shared__ float tile[32][33];
    const int b = blockIdx.x, tid = threadIdx.x;

    if (b < 2048) {                       // ---- cast x ----
        const int i = (b * 256 + tid) * 4;
        const float4 v = *(const float4*)(x + i);
        ushort4 o;
        o.x = f2bf(v.x); o.y = f2bf(v.y); o.z = f2bf(v.z); o.w = f2bf(v.w);
        *(ushort4*)(x_bf + i) = o;
        return;
    }
    if (b < 2560) {                       // ---- transpose w0a -> bT0 ----
        const int b2 = b - 2048;
        const int nb = (b2 & 31) * 32, kb = (b2 >> 5) * 32;
        const int tx = tid & 31, ty = tid >> 5;       // 32 x 8
#pragma unroll
        for (int i = 0; i < 4; ++i)
            tile[ty + i * 8][tx] = w0a[(size_t)(kb + ty + i * 8) * 1024 + nb + tx];
        __syncthreads();
#pragma unroll
        for (int i = 0; i < 4; ++i)
            bT0[(size_t)(nb + ty + i * 8) * 512 + kb + tx] = f2bf(tile[tx][ty + i * 8]);
        return;
    }
    if (b < 3616) {                       // ---- transpose w1a -> bT1 ----
        const int b3 = b - 2560;
        const int nb = (b3 & 31) * 32, kb = (b3 >> 5) * 32;   // kb up to 1055
        const int tx = tid & 31, ty = tid >> 5;
#pragma unroll
        for (int i = 0; i < 4; ++i) {
            const int k = kb + ty + i * 8;
            tile[ty + i * 8][tx] = (k < 1029) ? w1a[(size_t)k * 1024 + nb + tx] : 0.f;
        }
        __syncthreads();
#pragma unroll
        for (int i = 0; i < 4; ++i)
            bT1[(size_t)(nb + ty + i * 8) * 1056 + kb + tx] = f2bf(tile[tx][ty + i * 8]);
        return;
    }
    if (b < 4003) {                       // ---- wcomb 0/1 ----
        const int is1 = (b >= 3745);
        const int b4 = b - (is1 ? 3745 : 3616);
        const int w = tid >> 6, lane = tid & 63;
        const int row = b4 * 4 + w;
        const int F = is1 ? 1029 : 512;
        if (row > F) return;
        const float* wa = is1 ? w1a : w0a;
        const float* ba = is1 ? b1a : b0a;
        const float* wb = is1 ? w1b : w0b;
        const float* bb = is1 ? b1b : b0b;
        const float* src = (row < F) ? (wa + (size_t)row * 1024) : ba;
        float acc[15] = {};
        for (int h = lane; h < 1024; h += 64) {
            const float a = src[h];
            const float* wr = wb + h * 15;
#pragma unroll
            for (int c = 0; c < 15; ++c) acc[c] += a * wr[c];
        }
#pragma unroll
        for (int c = 0; c < 15; ++c)
#pragma unroll
            for (int off = 32; off > 0; off >>= 1) acc[c] += __shfl_xor(acc[c], off, 64);
        if (lane < 15) {
            if (row < F) {
                if (is1) bT1[(size_t)(1024 + lane) * 1056 + row] = f2bf(acc[lane]);
                else     bT0[(size_t)(1024 + lane) * 512  + row] = f2bf(acc[lane]);
            } else {
                if (is1) be1[1024 + lane] = acc[lane] + bb[lane];
                else     be0[1024 + lane] = acc[lane] + bb[lane];
            }
        }
        return;
    }
    {                                     // ---- bias copies ----
        const int b6 = b - 4003;
        if (b6 < 4) be0[b6 * 256 + tid] = b0a[b6 * 256 + tid];
        else        be1[(b6 - 4) * 256 + tid] = b1a[(b6 - 4) * 256 + tid];
    }
}

// ---------------------------------------------------------------------------
// bf16 MFMA GEMM: [h | t] = A[M,lda]bf16 @ (BT[NE,ldb]bf16)^T + be
// Block tile 64x128 (grid (9, M/64)=576: 2.25 blocks/CU — the 128x128 grid
// of 288 was 1.125/CU, badly unbalanced). 4 waves, wave tile 32x64
// (2x4 mfma, acc[2][4]). Staging: 3 global_load_lds w=16 per thread.
// Epilogue: cols <1024 -> h (ldc=1024); cols 1024..1038 -> compact t
// (stride 15, contiguous for diversity); cols >=1039 dropped.
// ---------------------------------------------------------------------------
__global__ __launch_bounds__(256)
void mfma_gemm(const unsigned short* __restrict__ A, int lda,
               const unsigned short* __restrict__ BT, int ldb,
               const float* __restrict__ bias, float* __restrict__ C,
               float* __restrict__ t, int K) {
    __shared__ unsigned short As[64 * 32];    // 4 KB
    __shared__ unsigned short Bs[128 * 32];   // 8 KB
    const int tid = threadIdx.x;
    const int w = tid >> 6, lane = tid & 63;
    const int q = lane >> 4, m16 = lane & 15;
    const int wr = (w >> 1) * 32, wc = (w & 1) * 64;
    const int br = blockIdx.y * 64, bc = blockIdx.x * 128;

    const int sr = tid >> 2;          // staging row 0..63
    const int sc = (tid & 3) * 8;     // staging col (elements)

    const unsigned short* gA0 = A + (size_t)(br + sr) * lda + sc;
    const unsigned short* gB0 = BT + (size_t)(bc + sr) * ldb + sc;
    const unsigned short* gB1 = BT + (size_t)(bc + sr + 64) * ldb + sc;
    unsigned short* lA0 = As + tid * 8;
    unsigned short* lB0 = Bs + tid * 8;
    unsigned short* lB1 = Bs + 64 * 32 + tid * 8;

    f32x4 acc[2][4] = {};

    for (int k0 = 0; k0 < K; k0 += 32) {
        ASYNC_CP16(gA0 + k0, lA0);
        ASYNC_CP16(gB0 + k0, lB0);
        ASYNC_CP16(gB1 + k0, lB1);
        __syncthreads();

        bf16x8 af[2], bfr[4];
#pragma unroll
        for (int i = 0; i < 2; ++i)
            af[i] = *(const bf16x8*)(As + (wr + 16 * i + m16) * 32 + q * 8);
#pragma unroll
        for (int j = 0; j < 4; ++j)
            bfr[j] = *(const bf16x8*)(Bs + (wc + 16 * j + m16) * 32 + q * 8);
#pragma unroll
        for (int i = 0; i < 2; ++i)
#pragma unroll
            for (int j = 0; j < 4; ++j)
                acc[i][j] = __builtin_amdgcn_mfma_f32_16x16x32_bf16(af[i], bfr[j], acc[i][j], 0, 0, 0);
        __syncthreads();
    }

#pragma unroll
    for (int i = 0; i < 2; ++i) {
        const int gr = br + wr + 16 * i + q * 4;
#pragma unroll
        for (int j = 0; j < 4; ++j) {
            const int gc = bc + wc + 16 * j + m16;
            if (gc < 1024) {
                const float b = bias[gc];
#pragma unroll
                for (int r = 0; r < 4; ++r)
                    C[(size_t)(gr + r) * 1024 + gc] = acc[i][j][r] + b;
            } else if (gc < 1039) {
                const float b = bias[gc];
#pragma unroll
                for (int r = 0; r < 4; ++r)
                    t[(size_t)(gr + r) * 15 + (gc - 1024)] = acc[i][j][r] + b;
            }
        }
    }
}

// ---------------------------------------------------------------------------
// Batch diversity: t (N,15 contiguous) -> dv_part (DIV_JC, N, 5).
// 2 i-rows/wave (52 VGPR — fits the compiler's pinned-64 target with NO
// scratch spill; 4-row needs ~110 live and spills regardless of
// launch_bounds: r5/r9 both show VGPR=64 + 20-27MB scratch WRITE).
// DIV_TI=8, grid (512,4)=2048 blocks -> 8 blocks/CU. Flat 15-float LDS rows
// (0 conflicts), contiguous t staging (r9/r10 read it at stride 1152 ->
// 15.5MB HBM FETCH; compact t restores ~1MB).
// ---------------------------------------------------------------------------
#define DIV_TI 8
#define DIV_JC 4
__global__ __launch_bounds__(256)
void diversity_kernel(const float* __restrict__ t, float* __restrict__ dv_part, int N) {
    const int tid = threadIdx.x;
    const int lane = tid & 63;
    const int g = tid >> 6;
    const int i0 = blockIdx.x * DIV_TI + g * 2;
    const int jbeg = blockIdx.y * (N / DIV_JC);
    const int jend = jbeg + N / DIV_JC;

    float ti[2][15];
#pragma unroll
    for (int r = 0; r < 2; ++r)
#pragma unroll
        for (int d = 0; d < 15; ++d)
            ti[r][d] = t[(i0 + r) * 15 + d];

    float acc[2][5] = {};

    __shared__ float tj_s[256 * 15];
    for (int j0 = jbeg; j0 < jend; j0 += 256) {
        __syncthreads();
#pragma unroll
        for (int it = 0; it < 15; ++it)
            tj_s[it * 256 + tid] = t[j0 * 15 + it * 256 + tid];  // straight copy
        __syncthreads();
#pragma unroll
        for (int m = 0; m < 4; ++m) {
            const float* rp = tj_s + (m * 64 + lane) * 15;
#pragma unroll
            for (int r = 0; r < 2; ++r) {
#pragma unroll
                for (int k = 0; k < 5; ++k) {
                    const float s = fabsf(ti[r][3 * k]     - rp[3 * k])
                                  + fabsf(ti[r][3 * k + 1] - rp[3 * k + 1])
                                  + fabsf(ti[r][3 * k + 2] - rp[3 * k + 2]);
                    acc[r][k] += __expf(-s);
                }
            }
        }
    }

#pragma unroll
    for (int r = 0; r < 2; ++r)
#pragma unroll
        for (int k = 0; k < 5; ++k)
#pragma unroll
            for (int off = 32; off > 0; off >>= 1)
                acc[r][k] += __shfl_xor(acc[r][k], off, 64);

    if (lane == 0) {
        float* dst = dv_part + (size_t)blockIdx.y * N * 5;
#pragma unroll
        for (int r = 0; r < 2; ++r)
#pragma unroll
            for (int k = 0; k < 5; ++k)
                dst[(i0 + r) * 5 + k] = acc[r][k];
    }
}

// ---------------------------------------------------------------------------
// concat([h, sum(dv_part)]) -> LN(center) -> LeakyReLU -> bf16 (M x Cp)
// ---------------------------------------------------------------------------
__global__ void ln_lrelu_mid(const float* __restrict__ h,
                             const float* __restrict__ dv_part,
                             const float* __restrict__ beta,
                             unsigned short* __restrict__ out_bf,
                             int H, int D, int Cp, int M) {
    const int i = blockIdx.x;
    const int tid = threadIdx.x;
    const int C = H + D;
    float v[5];
    float s = 0.f, s2 = 0.f;
#pragma unroll
    for (int r = 0; r < 5; ++r) {
        const int c = tid + r * 256;
        if (c < C) {
            float x;
            if (c < H) {
                x = h[(size_t)i * H + c];
            } else {
                const int k = c - H;
                x = 0.f;
#pragma unroll
                for (int jc = 0; jc < DIV_JC; ++jc)
                    x += dv_part[(size_t)jc * M * D + i * D + k];
            }
            v[r] = x; s += x; s2 += x * x;
        }
    }
    __shared__ float rs[4], rs2[4];
    const int lane = tid & 63, wave = tid >> 6;
#pragma unroll
    for (int off = 32; off > 0; off >>= 1) {
        s += __shfl_down(s, off, 64);
        s2 += __shfl_down(s2, off, 64);
    }
    if (lane == 0) { rs[wave] = s; rs2[wave] = s2; }
    __syncthreads();
    const float S = rs[0] + rs[1] + rs[2] + rs[3];
    const float S2 = rs2[0] + rs2[1] + rs2[2] + rs2[3];
    const float mu = S / (float)C;
    const float var = S2 / (float)C - mu * mu;
    const float rstd = rsqrtf(var + LN_EPS);
#pragma unroll
    for (int r = 0; r < 5; ++r) {
        const int c = tid + r * 256;
        if (c < C) {
            float y = (v[r] - mu) * rstd + beta[c];
            y = (y >= 0.f) ? y : LRELU_ALPHA * y;
            out_bf[(size_t)i * Cp + c] = f2bf(y);
        } else if (c < Cp) {
            out_bf[(size_t)i * Cp + c] = 0;  // zero K-pad for next MFMA GEMM
        }
    }
}

// ---------------------------------------------------------------------------
// Final: concat -> LN -> LeakyReLU -> fused head dot: out[i] = y.wf + bf
// ---------------------------------------------------------------------------
__global__ void ln_lrelu_head(const float* __restrict__ h,
                              const float* __restrict__ dv_part,
                              const float* __restrict__ beta, const float* __restrict__ wf,
                              const float* __restrict__ bfp, float* __restrict__ out,
                              int H, int D, int M) {
    const int i = blockIdx.x;
    const int tid = threadIdx.x;
    const int C = H + D;
    float v[5];
    float s = 0.f, s2 = 0.f;
#pragma unroll
    for (int r = 0; r < 5; ++r) {
        const int c = tid + r * 256;
        if (c < C) {
            float x;
            if (c < H) {
                x = h[(size_t)i * H + c];
            } else {
                const int k = c - H;
                x = 0.f;
#pragma unroll
                for (int jc = 0; jc < DIV_JC; ++jc)
                    x += dv_part[(size_t)jc * M * D + i * D + k];
            }
            v[r] = x; s += x; s2 += x * x;
        }
    }
    __shared__ float rs[4], rs2[4], rh[4];
    const int lane = tid & 63, wave = tid >> 6;
#pragma unroll
    for (int off = 32; off > 0; off >>= 1) {
        s += __shfl_down(s, off, 64);
        s2 += __shfl_down(s2, off, 64);
    }
    if (lane == 0) { rs[wave] = s; rs2[wave] = s2; }
    __syncthreads();
    const float S = rs[0] + rs[1] + rs[2] + rs[3];
    const float S2 = rs2[0] + rs2[1] + rs2[2] + rs2[3];
    const float mu = S / (float)C;
    const float var = S2 / (float)C - mu * mu;
    const float rstd = rsqrtf(var + LN_EPS);
    float hsum = 0.f;
#pragma unroll
    for (int r = 0; r < 5; ++r) {
        const int c = tid + r * 256;
        if (c < C) {
            float y = (v[r] - mu) * rstd + beta[c];
            y = (y >= 0.f) ? y : LRELU_ALPHA * y;
            hsum += y * wf[c];
        }
    }
#pragma unroll
    for (int off = 32; off > 0; off >>= 1) hsum += __shfl_down(hsum, off, 64);
    if (lane == 0) rh[wave] = hsum;
    __syncthreads();
    if (tid == 0) out[i] = rh[0] + rh[1] + rh[2] + rh[3] + bfp[0];
}

extern "C" void kernel_launch(void* const* d_in, const int* in_sizes, int n_in,
                              void* d_out, int out_size, void* d_ws, size_t ws_size,
                              hipStream_t stream) {
    const float* x     = (const float*)d_in[0];
    const float* w0a   = (const float*)d_in[1];
    const float* b0a   = (const float*)d_in[2];
    const float* w0b   = (const float*)d_in[3];
    const float* b0b   = (const float*)d_in[4];
    const float* beta0 = (const float*)d_in[5];
    const float* w1a   = (const float*)d_in[6];
    const float* b1a   = (const float*)d_in[7];
    const float* w1b   = (const float*)d_in[8];
    const float* b1b   = (const float*)d_in[9];
    const float* beta1 = (const float*)d_in[10];
    const float* wf    = (const float*)d_in[11];
    const float* bf    = (const float*)d_in[12];
    float* out = (float*)d_out;

    const int M = 4096, NF = 512, HID = 1024, CP = 1056;

    // fp32 workspace (all offsets multiple-of-4 floats -> 16B aligned)
    float* h   = (float*)d_ws;                      // 4096 x 1024
    float* t   = h   + (size_t)M * HID;             // 4096 x 15 (contiguous)
    float* dvp = t   + (size_t)M * 15;              // DIV_JC x 4096 x 5
    float* be0 = dvp + (size_t)DIV_JC * M * 5;      // 1152
    float* be1 = be0 + NE;                          // 1152
    // bf16 workspace (16B-aligned)
    unsigned short* x_bf = (unsigned short*)(be1 + NE);              // 4096 x 512
    unsigned short* hc_bf = x_bf + (size_t)M * NF;                   // 4096 x 1056
    unsigned short* bT0   = hc_bf + (size_t)M * CP;                  // 1152 x 512
    unsigned short* bT1   = bT0 + (size_t)NE * NF;                   // 1152 x 1056

    // ---- fused prep ----
    prep_kernel<<<4011, 256, 0, stream>>>(x, w0a, b0a, w0b, b0b, w1a, b1a, w1b, b1b,
                                          x_bf, bT0, bT1, be0, be1);

    // ---- layer 0: GEMM writes h (cols<1024) and compact t (cols 1024..1038) ----
    mfma_gemm<<<dim3(NE / 128, M / 64), 256, 0, stream>>>(x_bf, NF, bT0, NF, be0, h, t, NF);
    diversity_kernel<<<dim3(M / DIV_TI, DIV_JC), 256, 0, stream>>>(t, dvp, M);
    ln_lrelu_mid<<<M, 256, 0, stream>>>(h, dvp, beta0, hc_bf, HID, 5, CP, M);

    // ---- layer 1 ----
    mfma_gemm<<<dim3(NE / 128, M / 64), 256, 0, stream>>>(hc_bf, CP, bT1, CP, be1, h, t, CP);
    diversity_kernel<<<dim3(M / DIV_TI, DIV_JC), 256, 0, stream>>>(t, dvp, M);
    ln_lrelu_head<<<M, 256, 0, stream>>>(h, dvp, beta1, wf, bf, out, HID, 5, M);
}

// Round 12
// 215.732 us; speedup vs baseline: 1.4480x; 1.0014x over previous
//
#include <hip/hip_runtime.h>
#include <hip/hip_bf16.h>

#define LRELU_ALPHA 0.3f
#define LN_EPS 1e-3f

typedef short bf16x8 __attribute__((ext_vector_type(8)));
typedef float f32x4 __attribute__((ext_vector_type(4)));

static __device__ __forceinline__ unsigned short f2bf(float f) {
    union { float f; unsigned u; } v; v.f = f;
    unsigned r = v.u + 0x7fffu + ((v.u >> 16) & 1u);  // RNE
    return (unsigned short)(r >> 16);
}

// async 16B global -> LDS (DMA). LDS dest = wave-uniform base + lane*16.
#define ASYNC_CP16(gsrc, ldst)                                                  \
    __builtin_amdgcn_global_load_lds(                                           \
        (const __attribute__((address_space(1))) unsigned int*)(gsrc),          \
        (__attribute__((address_space(3))) unsigned int*)(ldst), 16, 0, 0)

#define NE 1152   // extended B-rows: 1024 hidden + 15 fused-skinny + pad

// ---------------------------------------------------------------------------
// Fused prep kernel (unchanged): cast x, transpose big weights, weight-combine
// skinny into B rows 1024..1038, extended biases.
// ---------------------------------------------------------------------------
__global__ void prep_kernel(const float* __restrict__ x,
                            const float* __restrict__ w0a, const float* __restrict__ b0a,
                            const float* __restrict__ w0b, const float* __restrict__ b0b,
                            const float* __restrict__ w1a, const float* __restrict__ b1a,
                            const float* __restrict__ w1b, const float* __restrict__ b1b,
                            unsigned short* __restrict__ x_bf,
                            unsigned short* __restrict__ bT0, unsigned short* __restrict__ bT1,
                            float* __restrict__ be0, float* __restrict__ be1) {
    __shared__ float tile[32][33];
    const int b = blockIdx.x, tid = threadIdx.x;

    if (b < 2048) {                       // ---- cast x ----
        const int i = (b * 256 + tid) * 4;
        const float4 v = *(const float4*)(x + i);
        ushort4 o;
        o.x = f2bf(v.x); o.y = f2bf(v.y); o.z = f2bf(v.z); o.w = f2bf(v.w);
        *(ushort4*)(x_bf + i) = o;
        return;
    }
    if (b < 2560) {                       // ---- transpose w0a -> bT0 ----
        const int b2 = b - 2048;
        const int nb = (b2 & 31) * 32, kb = (b2 >> 5) * 32;
        const int tx = tid & 31, ty = tid >> 5;       // 32 x 8
#pragma unroll
        for (int i = 0; i < 4; ++i)
            tile[ty + i * 8][tx] = w0a[(size_t)(kb + ty + i * 8) * 1024 + nb + tx];
        __syncthreads();
#pragma unroll
        for (int i = 0; i < 4; ++i)
            bT0[(size_t)(nb + ty + i * 8) * 512 + kb + tx] = f2bf(tile[tx][ty + i * 8]);
        return;
    }
    if (b < 3616) {                       // ---- transpose w1a -> bT1 ----
        const int b3 = b - 2560;
        const int nb = (b3 & 31) * 32, kb = (b3 >> 5) * 32;   // kb up to 1055
        const int tx = tid & 31, ty = tid >> 5;
#pragma unroll
        for (int i = 0; i < 4; ++i) {
            const int k = kb + ty + i * 8;
            tile[ty + i * 8][tx] = (k < 1029) ? w1a[(size_t)k * 1024 + nb + tx] : 0.f;
        }
        __syncthreads();
#pragma unroll
        for (int i = 0; i < 4; ++i)
            bT1[(size_t)(nb + ty + i * 8) * 1056 + kb + tx] = f2bf(tile[tx][ty + i * 8]);
        return;
    }
    if (b < 4003) {                       // ---- wcomb 0/1 ----
        const int is1 = (b >= 3745);
        const int b4 = b - (is1 ? 3745 : 3616);
        const int w = tid >> 6, lane = tid & 63;
        const int row = b4 * 4 + w;
        const int F = is1 ? 1029 : 512;
        if (row > F) return;
        const float* wa = is1 ? w1a : w0a;
        const float* ba = is1 ? b1a : b0a;
        const float* wb = is1 ? w1b : w0b;
        const float* bb = is1 ? b1b : b0b;
        const float* src = (row < F) ? (wa + (size_t)row * 1024) : ba;
        float acc[15] = {};
        for (int h = lane; h < 1024; h += 64) {
            const float a = src[h];
            const float* wr = wb + h * 15;
#pragma unroll
            for (int c = 0; c < 15; ++c) acc[c] += a * wr[c];
        }
#pragma unroll
        for (int c = 0; c < 15; ++c)
#pragma unroll
            for (int off = 32; off > 0; off >>= 1) acc[c] += __shfl_xor(acc[c], off, 64);
        if (lane < 15) {
            if (row < F) {
                if (is1) bT1[(size_t)(1024 + lane) * 1056 + row] = f2bf(acc[lane]);
                else     bT0[(size_t)(1024 + lane) * 512  + row] = f2bf(acc[lane]);
            } else {
                if (is1) be1[1024 + lane] = acc[lane] + bb[lane];
                else     be0[1024 + lane] = acc[lane] + bb[lane];
            }
        }
        return;
    }
    {                                     // ---- bias copies ----
        const int b6 = b - 4003;
        if (b6 < 4) be0[b6 * 256 + tid] = b0a[b6 * 256 + tid];
        else        be1[(b6 - 4) * 256 + tid] = b1a[(b6 - 4) * 256 + tid];
    }
}

// ---------------------------------------------------------------------------
// bf16 MFMA GEMM: [h | t] = A[M,lda]bf16 @ (BT[NE,ldb]bf16)^T + be
// Block tile 64x64 (small-GEMM TLP regime): grid (18,64)=1152 blocks =
// 4.5 blocks/CU = 18 waves/CU, vs r11's 64x128 grid of 576 = 2.25/CU which
// starved the CUs (m102: small-N GEMMs are latency-bound, not ladder-bound).
// 4 waves, wave tile 32x32 (acc[2][2]); staging = exactly one
// global_load_lds w=16 per thread for A and one for B; LDS 8 KB.
// Epilogue: cols <1024 -> h (ld 1024); cols 1024..1038 -> compact t (ld 15).
// ---------------------------------------------------------------------------
__global__ __launch_bounds__(256)
void mfma_gemm(const unsigned short* __restrict__ A, int lda,
               const unsigned short* __restrict__ BT, int ldb,
               const float* __restrict__ bias, float* __restrict__ C,
               float* __restrict__ t, int K) {
    __shared__ unsigned short As[64 * 32];    // 4 KB
    __shared__ unsigned short Bs[64 * 32];    // 4 KB
    const int tid = threadIdx.x;
    const int w = tid >> 6, lane = tid & 63;
    const int q = lane >> 4, m16 = lane & 15;
    const int wr = (w >> 1) * 32, wc = (w & 1) * 32;
    const int br = blockIdx.y * 64, bc = blockIdx.x * 64;

    const int sr = tid >> 2;          // staging row 0..63
    const int sc = (tid & 3) * 8;     // staging col (elements)

    const unsigned short* gA0 = A + (size_t)(br + sr) * lda + sc;
    const unsigned short* gB0 = BT + (size_t)(bc + sr) * ldb + sc;
    unsigned short* lA0 = As + tid * 8;
    unsigned short* lB0 = Bs + tid * 8;

    f32x4 acc[2][2] = {};

    for (int k0 = 0; k0 < K; k0 += 32) {
        ASYNC_CP16(gA0 + k0, lA0);
        ASYNC_CP16(gB0 + k0, lB0);
        __syncthreads();

        bf16x8 af[2], bfr[2];
#pragma unroll
        for (int i = 0; i < 2; ++i)
            af[i] = *(const bf16x8*)(As + (wr + 16 * i + m16) * 32 + q * 8);
#pragma unroll
        for (int j = 0; j < 2; ++j)
            bfr[j] = *(const bf16x8*)(Bs + (wc + 16 * j + m16) * 32 + q * 8);
#pragma unroll
        for (int i = 0; i < 2; ++i)
#pragma unroll
            for (int j = 0; j < 2; ++j)
                acc[i][j] = __builtin_amdgcn_mfma_f32_16x16x32_bf16(af[i], bfr[j], acc[i][j], 0, 0, 0);
        __syncthreads();
    }

#pragma unroll
    for (int i = 0; i < 2; ++i) {
        const int gr = br + wr + 16 * i + q * 4;
#pragma unroll
        for (int j = 0; j < 2; ++j) {
            const int gc = bc + wc + 16 * j + m16;
            if (gc < 1024) {
                const float b = bias[gc];
#pragma unroll
                for (int r = 0; r < 4; ++r)
                    C[(size_t)(gr + r) * 1024 + gc] = acc[i][j][r] + b;
            } else if (gc < 1039) {
                const float b = bias[gc];
#pragma unroll
                for (int r = 0; r < 4; ++r)
                    t[(size_t)(gr + r) * 15 + (gc - 1024)] = acc[i][j][r] + b;
            }
        }
    }
}

// ---------------------------------------------------------------------------
// Batch diversity (unchanged from r11): t (N,15 contiguous) -> dv_part.
// 2 i-rows/wave (no spill), flat 15-float LDS rows (0 conflicts),
// grid (512,4)=2048 blocks -> 8 blocks/CU.
// ---------------------------------------------------------------------------
#define DIV_TI 8
#define DIV_JC 4
__global__ __launch_bounds__(256)
void diversity_kernel(const float* __restrict__ t, float* __restrict__ dv_part, int N) {
    const int tid = threadIdx.x;
    const int lane = tid & 63;
    const int g = tid >> 6;
    const int i0 = blockIdx.x * DIV_TI + g * 2;
    const int jbeg = blockIdx.y * (N / DIV_JC);
    const int jend = jbeg + N / DIV_JC;

    float ti[2][15];
#pragma unroll
    for (int r = 0; r < 2; ++r)
#pragma unroll
        for (int d = 0; d < 15; ++d)
            ti[r][d] = t[(i0 + r) * 15 + d];

    float acc[2][5] = {};

    __shared__ float tj_s[256 * 15];
    for (int j0 = jbeg; j0 < jend; j0 += 256) {
        __syncthreads();
#pragma unroll
        for (int it = 0; it < 15; ++it)
            tj_s[it * 256 + tid] = t[j0 * 15 + it * 256 + tid];  // straight copy
        __syncthreads();
#pragma unroll
        for (int m = 0; m < 4; ++m) {
            const float* rp = tj_s + (m * 64 + lane) * 15;
#pragma unroll
            for (int r = 0; r < 2; ++r) {
#pragma unroll
                for (int k = 0; k < 5; ++k) {
                    const float s = fabsf(ti[r][3 * k]     - rp[3 * k])
                                  + fabsf(ti[r][3 * k + 1] - rp[3 * k + 1])
                                  + fabsf(ti[r][3 * k + 2] - rp[3 * k + 2]);
                    acc[r][k] += __expf(-s);
                }
            }
        }
    }

#pragma unroll
    for (int r = 0; r < 2; ++r)
#pragma unroll
        for (int k = 0; k < 5; ++k)
#pragma unroll
            for (int off = 32; off > 0; off >>= 1)
                acc[r][k] += __shfl_xor(acc[r][k], off, 64);

    if (lane == 0) {
        float* dst = dv_part + (size_t)blockIdx.y * N * 5;
#pragma unroll
        for (int r = 0; r < 2; ++r)
#pragma unroll
            for (int k = 0; k < 5; ++k)
                dst[(i0 + r) * 5 + k] = acc[r][k];
    }
}

// ---------------------------------------------------------------------------
// concat([h, sum(dv_part)]) -> LN(center) -> LeakyReLU -> bf16 (M x Cp)
// ---------------------------------------------------------------------------
__global__ void ln_lrelu_mid(const float* __restrict__ h,
                             const float* __restrict__ dv_part,
                             const float* __restrict__ beta,
                             unsigned short* __restrict__ out_bf,
                             int H, int D, int Cp, int M) {
    const int i = blockIdx.x;
    const int tid = threadIdx.x;
    const int C = H + D;
    float v[5];
    float s = 0.f, s2 = 0.f;
#pragma unroll
    for (int r = 0; r < 5; ++r) {
        const int c = tid + r * 256;
        if (c < C) {
            float x;
            if (c < H) {
                x = h[(size_t)i * H + c];
            } else {
                const int k = c - H;
                x = 0.f;
#pragma unroll
                for (int jc = 0; jc < DIV_JC; ++jc)
                    x += dv_part[(size_t)jc * M * D + i * D + k];
            }
            v[r] = x; s += x; s2 += x * x;
        }
    }
    __shared__ float rs[4], rs2[4];
    const int lane = tid & 63, wave = tid >> 6;
#pragma unroll
    for (int off = 32; off > 0; off >>= 1) {
        s += __shfl_down(s, off, 64);
        s2 += __shfl_down(s2, off, 64);
    }
    if (lane == 0) { rs[wave] = s; rs2[wave] = s2; }
    __syncthreads();
    const float S = rs[0] + rs[1] + rs[2] + rs[3];
    const float S2 = rs2[0] + rs2[1] + rs2[2] + rs2[3];
    const float mu = S / (float)C;
    const float var = S2 / (float)C - mu * mu;
    const float rstd = rsqrtf(var + LN_EPS);
#pragma unroll
    for (int r = 0; r < 5; ++r) {
        const int c = tid + r * 256;
        if (c < C) {
            float y = (v[r] - mu) * rstd + beta[c];
            y = (y >= 0.f) ? y : LRELU_ALPHA * y;
            out_bf[(size_t)i * Cp + c] = f2bf(y);
        } else if (c < Cp) {
            out_bf[(size_t)i * Cp + c] = 0;  // zero K-pad for next MFMA GEMM
        }
    }
}

// ---------------------------------------------------------------------------
// Final: concat -> LN -> LeakyReLU -> fused head dot: out[i] = y.wf + bf
// ---------------------------------------------------------------------------
__global__ void ln_lrelu_head(const float* __restrict__ h,
                              const float* __restrict__ dv_part,
                              const float* __restrict__ beta, const float* __restrict__ wf,
                              const float* __restrict__ bfp, float* __restrict__ out,
                              int H, int D, int M) {
    const int i = blockIdx.x;
    const int tid = threadIdx.x;
    const int C = H + D;
    float v[5];
    float s = 0.f, s2 = 0.f;
#pragma unroll
    for (int r = 0; r < 5; ++r) {
        const int c = tid + r * 256;
        if (c < C) {
            float x;
            if (c < H) {
                x = h[(size_t)i * H + c];
            } else {
                const int k = c - H;
                x = 0.f;
#pragma unroll
                for (int jc = 0; jc < DIV_JC; ++jc)
                    x += dv_part[(size_t)jc * M * D + i * D + k];
            }
            v[r] = x; s += x; s2 += x * x;
        }
    }
    __shared__ float rs[4], rs2[4], rh[4];
    const int lane = tid & 63, wave = tid >> 6;
#pragma unroll
    for (int off = 32; off > 0; off >>= 1) {
        s += __shfl_down(s, off, 64);
        s2 += __shfl_down(s2, off, 64);
    }
    if (lane == 0) { rs[wave] = s; rs2[wave] = s2; }
    __syncthreads();
    const float S = rs[0] + rs[1] + rs[2] + rs[3];
    const float S2 = rs2[0] + rs2[1] + rs2[2] + rs2[3];
    const float mu = S / (float)C;
    const float var = S2 / (float)C - mu * mu;
    const float rstd = rsqrtf(var + LN_EPS);
    float hsum = 0.f;
#pragma unroll
    for (int r = 0; r < 5; ++r) {
        const int c = tid + r * 256;
        if (c < C) {
            float y = (v[r] - mu) * rstd + beta[c];
            y = (y >= 0.f) ? y : LRELU_ALPHA * y;
            hsum += y * wf[c];
        }
    }
#pragma unroll
    for (int off = 32; off > 0; off >>= 1) hsum += __shfl_down(hsum, off, 64);
    if (lane == 0) rh[wave] = hsum;
    __syncthreads();
    if (tid == 0) out[i] = rh[0] + rh[1] + rh[2] + rh[3] + bfp[0];
}

extern "C" void kernel_launch(void* const* d_in, const int* in_sizes, int n_in,
                              void* d_out, int out_size, void* d_ws, size_t ws_size,
                              hipStream_t stream) {
    const float* x     = (const float*)d_in[0];
    const float* w0a   = (const float*)d_in[1];
    const float* b0a   = (const float*)d_in[2];
    const float* w0b   = (const float*)d_in[3];
    const float* b0b   = (const float*)d_in[4];
    const float* beta0 = (const float*)d_in[5];
    const float* w1a   = (const float*)d_in[6];
    const float* b1a   = (const float*)d_in[7];
    const float* w1b   = (const float*)d_in[8];
    const float* b1b   = (const float*)d_in[9];
    const float* beta1 = (const float*)d_in[10];
    const float* wf    = (const float*)d_in[11];
    const float* bf    = (const float*)d_in[12];
    float* out = (float*)d_out;

    const int M = 4096, NF = 512, HID = 1024, CP = 1056;

    // fp32 workspace (all offsets multiple-of-4 floats -> 16B aligned)
    float* h   = (float*)d_ws;                      // 4096 x 1024
    float* t   = h   + (size_t)M * HID;             // 4096 x 15 (contiguous)
    float* dvp = t   + (size_t)M * 15;              // DIV_JC x 4096 x 5
    float* be0 = dvp + (size_t)DIV_JC * M * 5;      // 1152
    float* be1 = be0 + NE;                          // 1152
    // bf16 workspace (16B-aligned)
    unsigned short* x_bf = (unsigned short*)(be1 + NE);              // 4096 x 512
    unsigned short* hc_bf = x_bf + (size_t)M * NF;                   // 4096 x 1056
    unsigned short* bT0   = hc_bf + (size_t)M * CP;                  // 1152 x 512
    unsigned short* bT1   = bT0 + (size_t)NE * NF;                   // 1152 x 1056

    // ---- fused prep ----
    prep_kernel<<<4011, 256, 0, stream>>>(x, w0a, b0a, w0b, b0b, w1a, b1a, w1b, b1b,
                                          x_bf, bT0, bT1, be0, be1);

    // ---- layer 0: GEMM writes h (cols<1024) and compact t (cols 1024..1038) ----
    mfma_gemm<<<dim3(NE / 64, M / 64), 256, 0, stream>>>(x_bf, NF, bT0, NF, be0, h, t, NF);
    diversity_kernel<<<dim3(M / DIV_TI, DIV_JC), 256, 0, stream>>>(t, dvp, M);
    ln_lrelu_mid<<<M, 256, 0, stream>>>(h, dvp, beta0, hc_bf, HID, 5, CP, M);

    // ---- layer 1 ----
    mfma_gemm<<<dim3(NE / 64, M / 64), 256, 0, stream>>>(hc_bf, CP, bT1, CP, be1, h, t, CP);
    diversity_kernel<<<dim3(M / DIV_TI, DIV_JC), 256, 0, stream>>>(t, dvp, M);
    ln_lrelu_head<<<M, 256, 0, stream>>>(h, dvp, beta1, wf, bf, out, HID, 5, M);
}